// Round 14
// baseline (3704.045 us; speedup 1.0000x reference)
//
#include <hip/hip_runtime.h>
#include <hip/hip_bf16.h>

// 12-layer GPT2-ish forward with LoRA + KV fake-quant, bf16 MFMA internals.
// B=4 T=1024 D=1024 H=16 HD=64 L=12 R=32, SCALING=2.0, EPS=1e-5, QMAX=255.

typedef __bf16 bf16x8 __attribute__((ext_vector_type(8)));
typedef float f32x4 __attribute__((ext_vector_type(4)));

static __device__ __forceinline__ float bf2f(unsigned short u) {
    union { unsigned int i; float f; } c; c.i = ((unsigned int)u) << 16; return c.f;
}
static __device__ __forceinline__ unsigned short f2bf(float f) {
    unsigned int u = __float_as_uint(f);
    u += 0x7fffu + ((u >> 16) & 1u);   // RNE
    return (unsigned short)(u >> 16);
}

// async global->LDS, 16B per lane; LDS dst must be wave-uniform (HW adds lane*16B)
#define GL2LDS(g, l) __builtin_amdgcn_global_load_lds( \
    (const __attribute__((address_space(1))) unsigned int*)(g), \
    (__attribute__((address_space(3))) unsigned int*)(l), 16, 0, 0)

// ---------------- embedding ----------------
__global__ __launch_bounds__(256) void k_embed(const int* __restrict__ ids,
        const float* __restrict__ wte, const float* __restrict__ wpe,
        float* __restrict__ h) {
    int row = blockIdx.x;          // b*1024 + t
    int t = row & 1023;
    int id = ids[row];
    int d = threadIdx.x * 4;
    float4 a = *(const float4*)(wte + (size_t)id * 1024 + d);
    float4 b = *(const float4*)(wpe + (size_t)t * 1024 + d);
    float4 o = make_float4(a.x + b.x, a.y + b.y, a.z + b.z, a.w + b.w);
    *(float4*)(h + (size_t)row * 1024 + d) = o;
}

// ---------------- layernorm (final, f32 out) ----------------
__global__ __launch_bounds__(256) void k_lnf(const float* __restrict__ h,
        const float* __restrict__ g, const float* __restrict__ be,
        float* __restrict__ fo) {
    int row = blockIdx.x, tid = threadIdx.x;
    float4 v = *(const float4*)(h + (size_t)row * 1024 + tid * 4);
    float s = v.x + v.y + v.z + v.w;
    for (int off = 32; off; off >>= 1) s += __shfl_down(s, off);
    __shared__ float red[8];
    int wid = tid >> 6, lane = tid & 63;
    if (!lane) red[wid] = s;
    __syncthreads();
    float mean = (red[0] + red[1] + red[2] + red[3]) * (1.f / 1024.f);
    float dx = v.x - mean, dy = v.y - mean, dz = v.z - mean, dw = v.w - mean;
    float q = dx * dx + dy * dy + dz * dz + dw * dw;
    for (int off = 32; off; off >>= 1) q += __shfl_down(q, off);
    if (!lane) red[4 + wid] = q;
    __syncthreads();
    float var = (red[4] + red[5] + red[6] + red[7]) * (1.f / 1024.f);
    float inv = 1.0f / sqrtf(var + 1e-5f);
    float4 gv = *(const float4*)(g + tid * 4);
    float4 bv = *(const float4*)(be + tid * 4);
    *(float4*)(fo + (size_t)row * 1024 + tid * 4) = make_float4(
        dx * inv * gv.x + bv.x, dy * inv * gv.y + bv.y,
        dz * inv * gv.z + bv.z, dw * inv * gv.w + bv.w);
}

// ---------------- fused LN + LoRA-A: xb = bf16(LN(h)); tmp = bf16(xb @ laT^T) ----------------
__global__ __launch_bounds__(512) void k_ln_lora(const float* __restrict__ h,
        const float* __restrict__ g, const float* __restrict__ be,
        const unsigned short* __restrict__ laT,
        unsigned short* __restrict__ xo, unsigned short* __restrict__ tmp) {
    __shared__ __align__(16) unsigned short Tx[16][1032];
    __shared__ f32x4 red[2][8][64];
    int tid = threadIdx.x;
    int r = tid >> 5;            // local row 0..15
    int lr = tid & 31;           // lane-in-row
    int row = blockIdx.x * 16 + r;
    const float* hrow = h + (size_t)row * 1024;
    float4 xv[8];
    float s = 0.f;
#pragma unroll
    for (int p = 0; p < 8; ++p) {
        xv[p] = *(const float4*)(hrow + p * 128 + lr * 4);
        s += (xv[p].x + xv[p].y) + (xv[p].z + xv[p].w);
    }
    s += __shfl_xor(s, 1); s += __shfl_xor(s, 2); s += __shfl_xor(s, 4);
    s += __shfl_xor(s, 8); s += __shfl_xor(s, 16);
    float mean = s * (1.f / 1024.f);
    float q = 0.f;
#pragma unroll
    for (int p = 0; p < 8; ++p) {
        float a = xv[p].x - mean, b = xv[p].y - mean;
        float c = xv[p].z - mean, d = xv[p].w - mean;
        q += (a * a + b * b) + (c * c + d * d);
    }
    q += __shfl_xor(q, 1); q += __shfl_xor(q, 2); q += __shfl_xor(q, 4);
    q += __shfl_xor(q, 8); q += __shfl_xor(q, 16);
    float inv = 1.0f / sqrtf(q * (1.f / 1024.f) + 1e-5f);
#pragma unroll
    for (int p = 0; p < 8; ++p) {
        int c0 = p * 128 + lr * 4;
        float4 gv = *(const float4*)(g + c0);
        float4 bv = *(const float4*)(be + c0);
        ushort4 o;
        o.x = f2bf((xv[p].x - mean) * inv * gv.x + bv.x);
        o.y = f2bf((xv[p].y - mean) * inv * gv.y + bv.y);
        o.z = f2bf((xv[p].z - mean) * inv * gv.z + bv.z);
        o.w = f2bf((xv[p].w - mean) * inv * gv.w + bv.w);
        *(ushort4*)(xo + (size_t)row * 1024 + c0) = o;
        *(ushort4*)&Tx[r][c0] = o;
    }
    __syncthreads();
    int w = tid >> 6, lane = tid & 63;
    int lrow = lane & 15, lk8 = (lane >> 4) * 8;
    f32x4 acc0 = {0.f, 0.f, 0.f, 0.f}, acc1 = {0.f, 0.f, 0.f, 0.f};
    const unsigned short* b0p = laT + (size_t)lrow * 1024 + w * 128 + lk8;
    const unsigned short* b1p = laT + (size_t)(16 + lrow) * 1024 + w * 128 + lk8;
#pragma unroll
    for (int kt = 0; kt < 128; kt += 32) {
        bf16x8 af = *(const bf16x8*)&Tx[lrow][w * 128 + kt + lk8];
        bf16x8 b0 = *(const bf16x8*)(b0p + kt);
        bf16x8 b1 = *(const bf16x8*)(b1p + kt);
        acc0 = __builtin_amdgcn_mfma_f32_16x16x32_bf16(af, b0, acc0, 0, 0, 0);
        acc1 = __builtin_amdgcn_mfma_f32_16x16x32_bf16(af, b1, acc1, 0, 0, 0);
    }
    red[0][w][lane] = acc0;
    red[1][w][lane] = acc1;
    __syncthreads();
    if (w == 0) {
        acc0 = ((red[0][0][lane] + red[0][1][lane]) + (red[0][2][lane] + red[0][3][lane]))
             + ((red[0][4][lane] + red[0][5][lane]) + (red[0][6][lane] + red[0][7][lane]));
        acc1 = ((red[1][0][lane] + red[1][1][lane]) + (red[1][2][lane] + red[1][3][lane]))
             + ((red[1][4][lane] + red[1][5][lane]) + (red[1][6][lane] + red[1][7][lane]));
        int lq = lane >> 4;
#pragma unroll
        for (int rg = 0; rg < 4; ++rg) {
            int orow = blockIdx.x * 16 + lq * 4 + rg;
            tmp[(size_t)orow * 64 + lrow] = f2bf(acc0[rg]);
            tmp[(size_t)orow * 64 + 16 + lrow] = f2bf(acc1[rg]);
            tmp[(size_t)orow * 64 + 32 + lrow] = 0;
            tmp[(size_t)orow * 64 + 48 + lrow] = 0;
        }
    }
}

// ---------------- LoRA-A via MFMA, 4-wave K-split (for ob / mb paths) ----------------
__global__ __launch_bounds__(256) void k_lora_mfma(const unsigned short* __restrict__ A,
        const unsigned short* __restrict__ laT, unsigned short* __restrict__ tmp, int K) {
    int rowBase = blockIdx.x * 16;
    int tid = threadIdx.x, w = tid >> 6, lane = tid & 63;
    int lrow = lane & 15, lk8 = (lane >> 4) * 8;
    int kq = K >> 2;
    f32x4 acc0 = {0.f, 0.f, 0.f, 0.f}, acc1 = {0.f, 0.f, 0.f, 0.f};
    const unsigned short* arow = A + (size_t)(rowBase + lrow) * K + w * kq + lk8;
    const unsigned short* b0p = laT + (size_t)lrow * K + w * kq + lk8;
    const unsigned short* b1p = laT + (size_t)(16 + lrow) * K + w * kq + lk8;
#pragma unroll 2
    for (int kt = 0; kt < kq; kt += 32) {
        bf16x8 af = *(const bf16x8*)(arow + kt);
        bf16x8 b0 = *(const bf16x8*)(b0p + kt);
        bf16x8 b1 = *(const bf16x8*)(b1p + kt);
        acc0 = __builtin_amdgcn_mfma_f32_16x16x32_bf16(af, b0, acc0, 0, 0, 0);
        acc1 = __builtin_amdgcn_mfma_f32_16x16x32_bf16(af, b1, acc1, 0, 0, 0);
    }
    __shared__ f32x4 red[2][4][64];
    red[0][w][lane] = acc0;
    red[1][w][lane] = acc1;
    __syncthreads();
    if (w == 0) {
        acc0 = red[0][0][lane] + red[0][1][lane] + red[0][2][lane] + red[0][3][lane];
        acc1 = red[1][0][lane] + red[1][1][lane] + red[1][2][lane] + red[1][3][lane];
        int lq = lane >> 4;
#pragma unroll
        for (int rg = 0; rg < 4; ++rg) {
            int row = rowBase + lq * 4 + rg;
            tmp[(size_t)row * 64 + lrow] = f2bf(acc0[rg]);
            tmp[(size_t)row * 64 + 16 + lrow] = f2bf(acc1[rg]);
            tmp[(size_t)row * 64 + 32 + lrow] = 0;
            tmp[(size_t)row * 64 + 48 + lrow] = 0;
        }
    }
}

// ---------------- batched weight prep (ALL layers, one launch): f32 [K][N] -> bf16 [N][K] ----------------
__global__ __launch_bounds__(256) void k_prep(
        const float* awB, const float* pwB, const float* fwB, const float* mwB,
        const float* albB, const float* plbB, const float* flbB, const float* mlbB,
        const float* alaB, const float* plaB, const float* flaB, const float* mlaB,
        unsigned short* WTqB, unsigned short* WTpB, unsigned short* WTfB, unsigned short* WTmB,
        unsigned short* LTqB, unsigned short* LTpB, unsigned short* LTfB, unsigned short* LTmB,
        unsigned short* LAqB, unsigned short* LApB, unsigned short* LAfB, unsigned short* LAmB) {
    int bid = blockIdx.x;
    size_t l = blockIdx.y;
    const float* src; unsigned short* dst; int K, N, ntn, local, dstS; float scale = 1.f;
    if      (bid < 768)  { src = awB + l*3145728;  dst = WTqB + l*3145728; K = 1024; N = 3072; ntn = 48; local = bid; dstS = K; }
    else if (bid < 1024) { src = pwB + l*1048576;  dst = WTpB + l*1048576; K = 1024; N = 1024; ntn = 16; local = bid - 768; dstS = K; }
    else if (bid < 2048) { src = fwB + l*4194304;  dst = WTfB + l*4194304; K = 1024; N = 4096; ntn = 64; local = bid - 1024; dstS = K; }
    else if (bid < 3072) { src = mwB + l*4194304;  dst = WTmB + l*4194304; K = 4096; N = 1024; ntn = 16; local = bid - 2048; dstS = K; }
    else if (bid < 3120) { src = albB + l*98304;   dst = LTqB + l*196608;  K = 32;   N = 3072; ntn = 48; local = bid - 3072; scale = 2.f; dstS = 64; }
    else if (bid < 3136) { src = plbB + l*32768;   dst = LTpB + l*65536;   K = 32;   N = 1024; ntn = 16; local = bid - 3120; scale = 2.f; dstS = 64; }
    else if (bid < 3200) { src = flbB + l*131072;  dst = LTfB + l*262144;  K = 32;   N = 4096; ntn = 64; local = bid - 3136; scale = 2.f; dstS = 64; }
    else if (bid < 3216) { src = mlbB + l*32768;   dst = LTmB + l*65536;   K = 32;   N = 1024; ntn = 16; local = bid - 3200; scale = 2.f; dstS = 64; }
    else if (bid < 3232) { src = alaB + l*32768;   dst = LAqB + l*32768;   K = 1024; N = 32;   ntn = 1;  local = bid - 3216; dstS = K; }
    else if (bid < 3248) { src = plaB + l*32768;   dst = LApB + l*32768;   K = 1024; N = 32;   ntn = 1;  local = bid - 3232; dstS = K; }
    else if (bid < 3264) { src = flaB + l*32768;   dst = LAfB + l*32768;   K = 1024; N = 32;   ntn = 1;  local = bid - 3248; dstS = K; }
    else                 { src = mlaB + l*131072;  dst = LAmB + l*131072;  K = 4096; N = 32;   ntn = 1;  local = bid - 3264; dstS = K; }
    int kt = local / ntn, nt = local % ntn;
    int k0 = kt * 64, n0 = nt * 64;
    __shared__ unsigned short Tl[64][66];
    int tid = threadIdx.x;
    int c4 = (tid & 15) * 4;
#pragma unroll
    for (int p = 0; p < 4; ++p) {
        int kl = p * 16 + (tid >> 4);
        if (k0 + kl < K && n0 + c4 < N) {
            float4 v = *(const float4*)(src + (size_t)(k0 + kl) * N + n0 + c4);
            ushort2 o0, o1;
            o0.x = f2bf(v.x * scale); o0.y = f2bf(v.y * scale);
            o1.x = f2bf(v.z * scale); o1.y = f2bf(v.w * scale);
            *(ushort2*)&Tl[kl][c4] = o0;
            *(ushort2*)&Tl[kl][c4 + 2] = o1;
        }
    }
    __syncthreads();
    int nl = tid >> 2;
    int kc = (tid & 3) * 8;
    if (n0 + nl < N) {
#pragma unroll
        for (int hh = 0; hh < 2; ++hh) {
            int kb = kc + hh * 32;
            if (k0 + kb < K) {
                unsigned short pk[8];
#pragma unroll
                for (int j = 0; j < 8; ++j) {
                    pk[j] = Tl[kb + j][nl];
                }
                *(uint4*)(dst + (size_t)(n0 + nl) * dstS + k0 + kb) = *(const uint4*)pk;
            } else if (k0 + kb < dstS) {
                uint4 z; z.x = 0; z.y = 0; z.z = 0; z.w = 0;
                *(uint4*)(dst + (size_t)(n0 + nl) * dstS + k0 + kb) = z;
            }
        }
    }
}

// ---------------- 128x128 8-phase GEMM (T2+T3+T4+T5, 4 waves) for proj / mproj ----------------
// EPI: 1 = +residual, write f32
template <int EPI>
__global__ __launch_bounds__(256, 1) void k_gemm128(
        const unsigned short* __restrict__ A, const unsigned short* __restrict__ WT,
        const float* __restrict__ bias, const unsigned short* __restrict__ tmpA,
        const unsigned short* __restrict__ lbT, const float* __restrict__ res,
        float* __restrict__ outF, int N, int K) {
    __shared__ unsigned short lds[9 * 4096];
    const int tid = threadIdx.x;
    const int wid = tid >> 6, lane = tid & 63;
    const int wr = wid >> 1, wc = wid & 1;          // 2x2 wave grid
    const int nBase = blockIdx.x * 128, rowBase = blockIdx.y * 128;
    const int nk = (K >> 6) + 1;                    // + LoRA K-tile

    f32x4 acc[4][4];
#pragma unroll
    for (int i = 0; i < 4; ++i)
#pragma unroll
        for (int j = 0; j < 4; ++j) acc[i][j] = f32x4{0.f, 0.f, 0.f, 0.f};

    auto stage = [&](int s) {
        int kt = s >> 2, part = s & 3;
        bool dead = kt >= nk;
        unsigned short* dst = &lds[(dead ? 8 : (s & 7)) * 4096];
        bool isA = part >= 2;
        int half = part & 1;
        bool lora = (kt == nk - 1);
#pragma unroll
        for (int i = 0; i < 2; ++i) {
            int o = ((i * 4 + wid) << 10) + (lane << 4);
            int r = o >> 7;
            int col = ((o & 127) ^ (((o >> 9) & 3) << 5)) >> 1;
            const unsigned short* src;
            if (dead) {
                src = A + (lane << 3);
            } else if (isA) {
                int grow = rowBase + half * 64 + r;
                src = lora ? tmpA + (size_t)grow * 64 + col
                           : A + (size_t)grow * K + kt * 64 + col;
            } else {
                int gcol = nBase + half * 64 + r;
                src = lora ? lbT + (size_t)gcol * 64 + col
                           : WT + (size_t)gcol * K + kt * 64 + col;
            }
            GL2LDS(src, dst + ((i * 4 + wid) << 9));
        }
    };

    stage(0); stage(1); stage(2); stage(3);
    stage(4); stage(5); stage(6);
    asm volatile("s_waitcnt vmcnt(6)" ::: "memory");
    __builtin_amdgcn_s_barrier();

    for (int kt = 0; kt < nk; ++kt) {
        const unsigned short* aPart = &lds[(((kt & 1) << 2) + 2 + wr) * 4096];
        const unsigned short* bPart = &lds[(((kt & 1) << 2) + wc) * 4096];
        bf16x8 bfr[4][2];
#pragma unroll
        for (int p = 0; p < 4; ++p) {
            bf16x8 af[2];
#pragma unroll
            for (int kk = 0; kk < 2; ++kk) {
                int row = p * 16 + (lane & 15);
                int cb = (kk * 64 + ((lane >> 4) << 4)) ^ (((row >> 2) & 3) << 5);
                af[kk] = *(const bf16x8*)&aPart[row * 64 + (cb >> 1)];
            }
            if (p == 0) {
#pragma unroll
                for (int n = 0; n < 4; ++n)
#pragma unroll
                    for (int kk = 0; kk < 2; ++kk) {
                        int row = n * 16 + (lane & 15);
                        int cb = (kk * 64 + ((lane >> 4) << 4)) ^ (((row >> 2) & 3) << 5);
                        bfr[n][kk] = *(const bf16x8*)&bPart[row * 64 + (cb >> 1)];
                    }
            }
            stage(p == 0 ? 4 * (kt + 1) + 3 : 4 * (kt + 2) + (p - 1));
            __builtin_amdgcn_s_barrier();
            __builtin_amdgcn_s_setprio(1);
#pragma unroll
            for (int n = 0; n < 4; ++n)
#pragma unroll
                for (int kk = 0; kk < 2; ++kk)
                    acc[p][n] = __builtin_amdgcn_mfma_f32_16x16x32_bf16(
                        af[kk], bfr[n][kk], acc[p][n], 0, 0, 0);
            __builtin_amdgcn_s_setprio(0);
            if (p == 3) asm volatile("s_waitcnt vmcnt(6)" ::: "memory");
            __builtin_amdgcn_s_barrier();
        }
    }

#pragma unroll
    for (int n = 0; n < 4; ++n) {
        int col = nBase + wc * 64 + n * 16 + (lane & 15);
        float bv = bias[col];
#pragma unroll
        for (int m = 0; m < 4; ++m) {
            int row0 = rowBase + wr * 64 + m * 16 + ((lane >> 4) << 2);
#pragma unroll
            for (int rg = 0; rg < 4; ++rg) {
                int row = row0 + rg;
                float v = acc[m][n][rg] + bv;
                size_t idx = (size_t)row * N + col;
                if (EPI == 1) v += res[idx];
                outF[idx] = v;
            }
        }
    }
}

// ---------------- 256x256 8-phase GEMM (T2+T3+T4+T5) for qkv / fc ----------------
// EPI: 2 = GELU, write bf16 ; 3 = fused head-split + KV fake-quant -> qh/kh/vh
template <int EPI>
__global__ __launch_bounds__(512, 1) void k_gemm256(
        const unsigned short* __restrict__ A, const unsigned short* __restrict__ WT,
        const float* __restrict__ bias, const unsigned short* __restrict__ tmpA,
        const unsigned short* __restrict__ lbT,
        const float* __restrict__ kvmin, const float* __restrict__ kvmax, int layer,
        unsigned short* __restrict__ qh, unsigned short* __restrict__ kh,
        unsigned short* __restrict__ vh,
        float* __restrict__ outF, unsigned short* __restrict__ outH, int N, int K) {
    __shared__ unsigned short lds[9 * 8192];
    const int tid = threadIdx.x;
    const int wid = tid >> 6, lane = tid & 63;
    const int wr = wid >> 2, wc = wid & 3;          // 2x4 wave grid
    const int nBase = blockIdx.x * 256, rowBase = blockIdx.y * 256;
    const int nk = (K >> 6) + 1;                    // + LoRA K-tile

    f32x4 acc[8][4];
#pragma unroll
    for (int i = 0; i < 8; ++i)
#pragma unroll
        for (int j = 0; j < 4; ++j) acc[i][j] = f32x4{0.f, 0.f, 0.f, 0.f};

    auto stage = [&](int s) {
        int kt = s >> 2, part = s & 3;
        bool dead = kt >= nk;
        unsigned short* dst = &lds[(dead ? 8 : (s & 7)) * 8192];
        bool isA = part >= 2;
        int half = part & 1;
        bool lora = (kt == nk - 1);
#pragma unroll
        for (int i = 0; i < 2; ++i) {
            int o = ((i * 8 + wid) << 10) + (lane << 4);
            int r = o >> 7;
            int col = ((o & 127) ^ (((o >> 9) & 3) << 5)) >> 1;
            const unsigned short* src;
            if (dead) {
                src = A + (lane << 3);
            } else if (isA) {
                int grow = rowBase + half * 128 + r;
                src = lora ? tmpA + (size_t)grow * 64 + col
                           : A + (size_t)grow * K + kt * 64 + col;
            } else {
                int gcol = nBase + half * 128 + r;
                src = lora ? lbT + (size_t)gcol * 64 + col
                           : WT + (size_t)gcol * K + kt * 64 + col;
            }
            GL2LDS(src, dst + ((i * 8 + wid) << 9));
        }
    };

    stage(0); stage(1); stage(2); stage(3);
    stage(4); stage(5); stage(6);
    asm volatile("s_waitcnt vmcnt(6)" ::: "memory");
    __builtin_amdgcn_s_barrier();

    for (int kt = 0; kt < nk; ++kt) {
        const unsigned short* aPart = &lds[(((kt & 1) << 2) + 2 + wr) * 8192];
        const unsigned short* bPart = &lds[(((kt & 1) << 2) + (wc >> 1)) * 8192];
        bf16x8 bfr[4][2];
#pragma unroll
        for (int p = 0; p < 4; ++p) {
            bf16x8 af[2][2];
#pragma unroll
            for (int mm = 0; mm < 2; ++mm)
#pragma unroll
                for (int kk = 0; kk < 2; ++kk) {
                    int row = (p * 2 + mm) * 16 + (lane & 15);
                    int cb = (kk * 64 + ((lane >> 4) << 4)) ^ (((row >> 2) & 3) << 5);
                    af[mm][kk] = *(const bf16x8*)&aPart[row * 64 + (cb >> 1)];
                }
            if (p == 0) {
#pragma unroll
                for (int n = 0; n < 4; ++n)
#pragma unroll
                    for (int kk = 0; kk < 2; ++kk) {
                        int row = ((wc & 1) << 6) + n * 16 + (lane & 15);
                        int cb = (kk * 64 + ((lane >> 4) << 4)) ^ (((row >> 2) & 3) << 5);
                        bfr[n][kk] = *(const bf16x8*)&bPart[row * 64 + (cb >> 1)];
                    }
            }
            stage(p == 0 ? 4 * (kt + 1) + 3 : 4 * (kt + 2) + (p - 1));
            __builtin_amdgcn_s_barrier();
            __builtin_amdgcn_s_setprio(1);
#pragma unroll
            for (int mm = 0; mm < 2; ++mm)
#pragma unroll
                for (int n = 0; n < 4; ++n)
#pragma unroll
                    for (int kk = 0; kk < 2; ++kk)
                        acc[p * 2 + mm][n] = __builtin_amdgcn_mfma_f32_16x16x32_bf16(
                            af[mm][kk], bfr[n][kk], acc[p * 2 + mm][n], 0, 0, 0);
            __builtin_amdgcn_s_setprio(0);
            if (p == 3) asm volatile("s_waitcnt vmcnt(6)" ::: "memory");
            __builtin_amdgcn_s_barrier();
        }
    }

    if (EPI == 3) {
        const int b = rowBase >> 10, t0 = rowBase & 1023;
        const int sec = nBase >> 10, nb = nBase & 1023;
        const int lrow = lane & 15, lq4 = (lane >> 4) << 2;
        float qs = 1.f, qzp = 0.f, qinv = 1.f;
        if (sec) {
            float mnv = kvmin[layer], mxv = kvmax[layer];
            qs = (mxv - mnv) * (1.f / 255.f);
            qzp = rintf(-mnv / qs);
            qinv = 1.f / qs;
        }
#pragma unroll
        for (int n = 0; n < 4; ++n) {
            int dd = wc * 64 + n * 16 + lrow;
            float bv = bias[nBase + dd];
#pragma unroll
            for (int m = 0; m < 8; ++m) {
#pragma unroll
                for (int rg = 0; rg < 4; ++rg) {
                    int tt = wr * 128 + m * 16 + lq4 + rg;
                    float v = acc[m][n][rg] + bv;
                    if (sec) {
                        float qv = rintf(v * qinv) + qzp;
                        qv = fminf(fmaxf(qv, 0.f), 255.f);
                        v = (qv - qzp) * qs;
                    }
                    int r = (sec == 2) ? dd : tt;
                    int c = (sec == 2) ? tt : dd;
                    lds[r * 256 + (c ^ ((r & 7) << 3))] = f2bf(v);
                }
            }
        }
        __syncthreads();
        if (sec < 2) {
            unsigned short* dstp = sec ? kh : qh;
            int tL = tid & 255;
            int hp = tid >> 8;
#pragma unroll
            for (int hi = 0; hi < 2; ++hi) {
                int dL = (hp * 2 + hi) * 64;
                int hh = (nb >> 6) + hp * 2 + hi;
                size_t base = (((size_t)(b * 16 + hh)) * 1024 + t0 + tL) * 64;
#pragma unroll
                for (int j = 0; j < 8; ++j) {
                    int c = (dL + j * 8) ^ ((tL & 7) << 3);
                    *(uint4*)(dstp + base + j * 8) = *(const uint4*)&lds[tL * 256 + c];
                }
            }
        } else {
            int dL = tid & 255;
            int th = (tid >> 8) * 128;
            int hh = (nb >> 6) + (dL >> 6);
            size_t base = (((size_t)(b * 16 + hh)) * 64 + (dL & 63)) * 1024 + t0 + th;
#pragma unroll
            for (int j = 0; j < 16; ++j) {
                int c = (th + j * 8) ^ ((dL & 7) << 3);
                *(uint4*)(vh + base + j * 8) = *(const uint4*)&lds[dL * 256 + c];
            }
        }
    } else {
#pragma unroll
        for (int n = 0; n < 4; ++n) {
            int col = nBase + wc * 64 + n * 16 + (lane & 15);
            float bv = bias[col];
#pragma unroll
            for (int m = 0; m < 8; ++m) {
                int row0 = rowBase + wr * 128 + m * 16 + ((lane >> 4) << 2);
#pragma unroll
                for (int rg = 0; rg < 4; ++rg) {
                    int row = row0 + rg;
                    float v = acc[m][n][rg] + bv;
                    size_t idx = (size_t)row * N + col;
                    v = 0.5f * v * (1.f + erff(v * 0.70710678118654752f));
                    outH[idx] = f2bf(v);
                }
            }
        }
    }
}

// ---------------- flash attention (causal), 128 q-rows/block, 4 waves ----------------
// swapped QK^T; wave owns 32 q-rows (2 subtiles of 16). K/V staging amortized over 2x q-rows;
// fully-masked tiles for lower subtiles are exact no-ops (exp2 underflow to 0, corr=1).
__global__ __launch_bounds__(256) void k_attn(const unsigned short* __restrict__ qh,
        const unsigned short* __restrict__ kh, const unsigned short* __restrict__ vh,
        unsigned short* __restrict__ o) {
    // bijective XCD swizzle: 512 blocks, 8 XCDs -> 64-block contiguous runs per XCD
    int fid = blockIdx.y * 8 + blockIdx.x;
    int wgid = (fid & 7) * 64 + (fid >> 3);
    int bh = wgid >> 3, qb2 = wgid & 7;
    int b = bh >> 4, hh = bh & 15;
    int tid = threadIdx.x, w = tid >> 6, lane = tid & 63;
    int cq = lane & 15;
    int g = lane >> 4;
    int lk8 = g * 8;
    __shared__ unsigned short Kl[64][72];
    __shared__ unsigned short Vt[64][72];
    __shared__ unsigned short Pl[4][32][72];
    const float SCL = 0.18033688011112042f;   // 0.125 * log2(e)
    int qbase = qb2 * 128 + w * 32;
    bf16x8 aq[2][2];
#pragma unroll
    for (int sub = 0; sub < 2; ++sub) {
        int qrow = qbase + sub * 16 + cq;
        aq[sub][0] = *(const bf16x8*)(qh + ((size_t)bh * 1024 + qrow) * 64 + lk8);
        aq[sub][1] = *(const bf16x8*)(qh + ((size_t)bh * 1024 + qrow) * 64 + 32 + lk8);
    }
    f32x4 od[2][4];
#pragma unroll
    for (int sub = 0; sub < 2; ++sub)
#pragma unroll
        for (int i = 0; i < 4; ++i) od[sub][i] = f32x4{0.f, 0.f, 0.f, 0.f};
    float mrun[2] = {-3e38f, -3e38f}, lrun[2] = {0.f, 0.f};
    int rl = tid >> 2, seg = (tid & 3) * 16;
    int kbMax = qb2 * 2 + 1;
    for (int kb = 0; kb <= kbMax; ++kb) {
        __syncthreads();
        {
            size_t kbase = ((size_t)bh * 1024 + kb * 64 + rl) * 64 + seg;
            *(uint4*)&Kl[rl][seg] = *(const uint4*)(kh + kbase);
            *(uint4*)&Kl[rl][seg + 8] = *(const uint4*)(kh + kbase + 8);
            size_t vbase = ((size_t)bh * 64 + rl) * 1024 + kb * 64 + seg;
            *(uint4*)&Vt[rl][seg] = *(const uint4*)(vh + vbase);
            *(uint4*)&Vt[rl][seg + 8] = *(const uint4*)(vh + vbase + 8);
        }
        __syncthreads();
        f32x4 st[2][4];
#pragma unroll
        for (int ktile = 0; ktile < 4; ++ktile) {
            bf16x8 bk0 = *(const bf16x8*)&Kl[ktile * 16 + cq][lk8];
            bf16x8 bk1 = *(const bf16x8*)&Kl[ktile * 16 + cq][32 + lk8];
#pragma unroll
            for (int sub = 0; sub < 2; ++sub) {
                f32x4 sacc = f32x4{0.f, 0.f, 0.f, 0.f};
                sacc = __builtin_amdgcn_mfma_f32_16x16x32_bf16(bk0, aq[sub][0], sacc, 0, 0, 0);
                sacc = __builtin_amdgcn_mfma_f32_16x16x32_bf16(bk1, aq[sub][1], sacc, 0, 0, 0);
                st[sub][ktile] = sacc * SCL;
            }
        }
#pragma unroll
        for (int sub = 0; sub < 2; ++sub) {
            int qrow = qbase + sub * 16 + cq;
            // causal mask (also handles whole-tile overshoot for lower subtile)
            if (kb * 64 + 63 > qrow) {
#pragma unroll
                for (int ktile = 0; ktile < 4; ++ktile)
#pragma unroll
                    for (int rg = 0; rg < 4; ++rg) {
                        int kidx = kb * 64 + ktile * 16 + g * 4 + rg;
                        if (kidx > qrow) st[sub][ktile][rg] = -3e38f;
                    }
            }
            float tm[4];
#pragma unroll
            for (int ktile = 0; ktile < 4; ++ktile)
                tm[ktile] = fmaxf(fmaxf(st[sub][ktile][0], st[sub][ktile][1]),
                                  fmaxf(st[sub][ktile][2], st[sub][ktile][3]));
            float pmax = fmaxf(fmaxf(tm[0], tm[1]), fmaxf(tm[2], tm[3]));
            pmax = fmaxf(pmax, __shfl_xor(pmax, 16));
            pmax = fmaxf(pmax, __shfl_xor(pmax, 32));
            float mnew = fmaxf(mrun[sub], pmax);
#pragma unroll
            for (int ktile = 0; ktile < 4; ++ktile)
#pragma unroll
                for (int rg = 0; rg < 4; ++rg)
                    st[sub][ktile][rg] = exp2f(st[sub][ktile][rg] - mnew);
            float ts[4];
#pragma unroll
            for (int ktile = 0; ktile < 4; ++ktile)
                ts[ktile] = (st[sub][ktile][0] + st[sub][ktile][1])
                          + (st[sub][ktile][2] + st[sub][ktile][3]);
            float sum = (ts[0] + ts[1]) + (ts[2] + ts[3]);
            sum += __shfl_xor(sum, 16);
            sum += __shfl_xor(sum, 32);
            float corr = exp2f(mrun[sub] - mnew);
            lrun[sub] = lrun[sub] * corr + sum;
            mrun[sub] = mnew;
#pragma unroll
            for (int rg = 0; rg < 4; ++rg) {
                float cv = __shfl(corr, (lane & 48) | (g * 4 + rg));
#pragma unroll
                for (int dt = 0; dt < 4; ++dt) od[sub][dt][rg] *= cv;
            }
#pragma unroll
            for (int ktile = 0; ktile < 4; ++ktile) {
                ushort4 pw;
                pw.x = f2bf(st[sub][ktile][0]); pw.y = f2bf(st[sub][ktile][1]);
                pw.z = f2bf(st[sub][ktile][2]); pw.w = f2bf(st[sub][ktile][3]);
                *(ushort4*)&Pl[w][sub * 16 + cq][ktile * 16 + g * 4] = pw;
            }
        }
#pragma unroll
        for (int dt = 0; dt < 4; ++dt) {
            bf16x8 bv0 = *(const bf16x8*)&Vt[dt * 16 + cq][lk8];
            bf16x8 bv1 = *(const bf16x8*)&Vt[dt * 16 + cq][32 + lk8];
#pragma unroll
            for (int sub = 0; sub < 2; ++sub) {
                bf16x8 pa0 = *(const bf16x8*)&Pl[w][sub * 16 + cq][lk8];
                bf16x8 pa1 = *(const bf16x8*)&Pl[w][sub * 16 + cq][32 + lk8];
                od[sub][dt] = __builtin_amdgcn_mfma_f32_16x16x32_bf16(pa0, bv0, od[sub][dt], 0, 0, 0);
                od[sub][dt] = __builtin_amdgcn_mfma_f32_16x16x32_bf16(pa1, bv1, od[sub][dt], 0, 0, 0);
            }
        }
    }
#pragma unroll
    for (int sub = 0; sub < 2; ++sub)
#pragma unroll
    for (int rg = 0; rg < 4; ++rg) {
        float lv = __shfl(lrun[sub], (lane & 48) | (g * 4 + rg));
        float inv = 1.0f / lv;
        int row = qbase + sub * 16 + g * 4 + rg;
#pragma unroll
        for (int dt = 0; dt < 4; ++dt) {
            float val = od[sub][dt][rg] * inv;
            o[((size_t)(b * 1024 + row)) * 1024 + hh * 64 + dt * 16 + cq] = f2bf(val);
        }
    }
}

// ---------------- host orchestration ----------------
extern "C" void kernel_launch(void* const* d_in, const int* in_sizes, int n_in,
                              void* d_out, int out_size, void* d_ws, size_t ws_size,
                              hipStream_t stream) {
    const int*   ids      = (const int*)d_in[0];
    const float* wte      = (const float*)d_in[1];
    const float* wpe      = (const float*)d_in[2];
    const float* ln1_g    = (const float*)d_in[3];
    const float* ln1_b    = (const float*)d_in[4];
    const float* attn_w   = (const float*)d_in[5];
    const float* attn_b   = (const float*)d_in[6];
    const float* attn_la  = (const float*)d_in[7];
    const float* attn_lb  = (const float*)d_in[8];
    const float* proj_w   = (const float*)d_in[9];
    const float* proj_b   = (const float*)d_in[10];
    const float* proj_la  = (const float*)d_in[11];
    const float* proj_lb  = (const float*)d_in[12];
    const float* ln2_g    = (const float*)d_in[13];
    const float* ln2_b    = (const float*)d_in[14];
    const float* fc_w     = (const float*)d_in[15];
    const float* fc_b     = (const float*)d_in[16];
    const float* fc_la    = (const float*)d_in[17];
    const float* fc_lb    = (const float*)d_in[18];
    const float* mproj_w  = (const float*)d_in[19];
    const float* mproj_b  = (const float*)d_in[20];
    const float* mproj_la = (const float*)d_in[21];
    const float* mproj_lb = (const float*)d_in[22];
    const float* kv_min   = (const float*)d_in[23];
    const float* kv_max   = (const float*)d_in[24];
    const float* lnf_g    = (const float*)d_in[25];
    const float* lnf_b    = (const float*)d_in[26];

    char* ws = (char*)d_ws;
    size_t off = 0;
    auto alloc = [&](size_t bytes) -> char* {
        char* p = ws + off;
        off = (off + bytes + 255) & ~(size_t)255;
        return p;
    };
    float*          h   = (float*)alloc(4096ull * 1024 * 4);
    unsigned short* xb  = (unsigned short*)alloc(4096ull * 1024 * 2);
    unsigned short* tmp = (unsigned short*)alloc(4096ull * 64 * 2);
    unsigned short* qhb = (unsigned short*)alloc(64ull * 1024 * 64 * 2);
    unsigned short* khb = (unsigned short*)alloc(64ull * 1024 * 64 * 2);
    unsigned short* vhb = (unsigned short*)alloc(64ull * 64 * 1024 * 2);
    unsigned short* ob  = (unsigned short*)alloc(4096ull * 1024 * 2);
    unsigned short* mb  = (unsigned short*)alloc(4096ull * 4096 * 2);
    unsigned short* WTq = (unsigned short*)alloc(12ull * 3072 * 1024 * 2);
    unsigned short* WTp = (unsigned short*)alloc(12ull * 1024 * 1024 * 2);
    unsigned short* WTf = (unsigned short*)alloc(12ull * 4096 * 1024 * 2);
    unsigned short* WTm = (unsigned short*)alloc(12ull * 1024 * 4096 * 2);
    unsigned short* LTq = (unsigned short*)alloc(12ull * 3072 * 64 * 2);
    unsigned short* LTp = (unsigned short*)alloc(12ull * 1024 * 64 * 2);
    unsigned short* LTf = (unsigned short*)alloc(12ull * 4096 * 64 * 2);
    unsigned short* LTm = (unsigned short*)alloc(12ull * 1024 * 64 * 2);
    unsigned short* LAq = (unsigned short*)alloc(12ull * 32 * 1024 * 2);
    unsigned short* LAp = (unsigned short*)alloc(12ull * 32 * 1024 * 2);
    unsigned short* LAf = (unsigned short*)alloc(12ull * 32 * 1024 * 2);
    unsigned short* LAm = (unsigned short*)alloc(12ull * 32 * 4096 * 2);

    k_embed<<<4096, 256, 0, stream>>>(ids, wte, wpe, h);
    k_prep<<<dim3(3328, 12), 256, 0, stream>>>(
        attn_w, proj_w, fc_w, mproj_w,
        attn_lb, proj_lb, fc_lb, mproj_lb,
        attn_la, proj_la, fc_la, mproj_la,
        WTq, WTp, WTf, WTm, LTq, LTp, LTf, LTm, LAq, LAp, LAf, LAm);
    for (int l = 0; l < 12; ++l) {
        k_ln_lora<<<256, 512, 0, stream>>>(h, ln1_g + l * 1024, ln1_b + l * 1024,
                                           LAq + (size_t)l * 32768, xb, tmp);
        k_gemm256<3><<<dim3(12, 16), 512, 0, stream>>>(xb, WTq + (size_t)l * 3145728,
                                                       attn_b + l * 3072, tmp, LTq + (size_t)l * 196608,
                                                       kv_min, kv_max, l, qhb, khb, vhb,
                                                       nullptr, nullptr, 3072, 1024);
        k_attn<<<dim3(8, 64), 256, 0, stream>>>(qhb, khb, vhb, ob);
        k_lora_mfma<<<256, 256, 0, stream>>>(ob, LAp + (size_t)l * 32768, tmp, 1024);
        k_gemm128<1><<<dim3(8, 32), 256, 0, stream>>>(ob, WTp + (size_t)l * 1048576,
                                                      proj_b + l * 1024, tmp, LTp + (size_t)l * 65536,
                                                      h, h, 1024, 1024);
        k_ln_lora<<<256, 512, 0, stream>>>(h, ln2_g + l * 1024, ln2_b + l * 1024,
                                           LAf + (size_t)l * 32768, xb, tmp);
        k_gemm256<2><<<dim3(16, 16), 512, 0, stream>>>(xb, WTf + (size_t)l * 4194304,
                                                       fc_b + l * 4096, tmp, LTf + (size_t)l * 262144,
                                                       nullptr, nullptr, 0, nullptr, nullptr, nullptr,
                                                       nullptr, mb, 4096, 1024);
        k_lora_mfma<<<256, 256, 0, stream>>>(mb, LAm + (size_t)l * 131072, tmp, 4096);
        k_gemm128<1><<<dim3(8, 32), 256, 0, stream>>>(mb, WTm + (size_t)l * 4194304,
                                                      mproj_b + l * 1024, tmp, LTm + (size_t)l * 65536,
                                                      h, h, 1024, 4096);
    }
    k_lnf<<<4096, 256, 0, stream>>>(h, lnf_g, lnf_b, (float*)d_out);
}

// Round 15
// 3549.723 us; speedup vs baseline: 1.0435x; 1.0435x over previous
//
#include <hip/hip_runtime.h>
#include <hip/hip_bf16.h>

// 12-layer GPT2-ish forward with LoRA + KV fake-quant, bf16 MFMA internals.
// B=4 T=1024 D=1024 H=16 HD=64 L=12 R=32, SCALING=2.0, EPS=1e-5, QMAX=255.

typedef __bf16 bf16x8 __attribute__((ext_vector_type(8)));
typedef float f32x4 __attribute__((ext_vector_type(4)));

static __device__ __forceinline__ float bf2f(unsigned short u) {
    union { unsigned int i; float f; } c; c.i = ((unsigned int)u) << 16; return c.f;
}
static __device__ __forceinline__ unsigned short f2bf(float f) {
    unsigned int u = __float_as_uint(f);
    u += 0x7fffu + ((u >> 16) & 1u);   // RNE
    return (unsigned short)(u >> 16);
}

// async global->LDS, 16B per lane; LDS dst must be wave-uniform (HW adds lane*16B)
#define GL2LDS(g, l) __builtin_amdgcn_global_load_lds( \
    (const __attribute__((address_space(1))) unsigned int*)(g), \
    (__attribute__((address_space(3))) unsigned int*)(l), 16, 0, 0)

// ---------------- embedding ----------------
__global__ __launch_bounds__(256) void k_embed(const int* __restrict__ ids,
        const float* __restrict__ wte, const float* __restrict__ wpe,
        float* __restrict__ h) {
    int row = blockIdx.x;          // b*1024 + t
    int t = row & 1023;
    int id = ids[row];
    int d = threadIdx.x * 4;
    float4 a = *(const float4*)(wte + (size_t)id * 1024 + d);
    float4 b = *(const float4*)(wpe + (size_t)t * 1024 + d);
    float4 o = make_float4(a.x + b.x, a.y + b.y, a.z + b.z, a.w + b.w);
    *(float4*)(h + (size_t)row * 1024 + d) = o;
}

// ---------------- layernorm (final, f32 out) ----------------
__global__ __launch_bounds__(256) void k_lnf(const float* __restrict__ h,
        const float* __restrict__ g, const float* __restrict__ be,
        float* __restrict__ fo) {
    int row = blockIdx.x, tid = threadIdx.x;
    float4 v = *(const float4*)(h + (size_t)row * 1024 + tid * 4);
    float s = v.x + v.y + v.z + v.w;
    for (int off = 32; off; off >>= 1) s += __shfl_down(s, off);
    __shared__ float red[8];
    int wid = tid >> 6, lane = tid & 63;
    if (!lane) red[wid] = s;
    __syncthreads();
    float mean = (red[0] + red[1] + red[2] + red[3]) * (1.f / 1024.f);
    float dx = v.x - mean, dy = v.y - mean, dz = v.z - mean, dw = v.w - mean;
    float q = dx * dx + dy * dy + dz * dz + dw * dw;
    for (int off = 32; off; off >>= 1) q += __shfl_down(q, off);
    if (!lane) red[4 + wid] = q;
    __syncthreads();
    float var = (red[4] + red[5] + red[6] + red[7]) * (1.f / 1024.f);
    float inv = 1.0f / sqrtf(var + 1e-5f);
    float4 gv = *(const float4*)(g + tid * 4);
    float4 bv = *(const float4*)(be + tid * 4);
    *(float4*)(fo + (size_t)row * 1024 + tid * 4) = make_float4(
        dx * inv * gv.x + bv.x, dy * inv * gv.y + bv.y,
        dz * inv * gv.z + bv.z, dw * inv * gv.w + bv.w);
}

// ---------------- fused LN + LoRA-A: xb = bf16(LN(h)); tmp = bf16(xb @ laT^T) ----------------
__global__ __launch_bounds__(512) void k_ln_lora(const float* __restrict__ h,
        const float* __restrict__ g, const float* __restrict__ be,
        const unsigned short* __restrict__ laT,
        unsigned short* __restrict__ xo, unsigned short* __restrict__ tmp) {
    __shared__ __align__(16) unsigned short Tx[16][1032];
    __shared__ f32x4 red[2][8][64];
    int tid = threadIdx.x;
    int r = tid >> 5;            // local row 0..15
    int lr = tid & 31;           // lane-in-row
    int row = blockIdx.x * 16 + r;
    const float* hrow = h + (size_t)row * 1024;
    float4 xv[8];
    float s = 0.f;
#pragma unroll
    for (int p = 0; p < 8; ++p) {
        xv[p] = *(const float4*)(hrow + p * 128 + lr * 4);
        s += (xv[p].x + xv[p].y) + (xv[p].z + xv[p].w);
    }
    s += __shfl_xor(s, 1); s += __shfl_xor(s, 2); s += __shfl_xor(s, 4);
    s += __shfl_xor(s, 8); s += __shfl_xor(s, 16);
    float mean = s * (1.f / 1024.f);
    float q = 0.f;
#pragma unroll
    for (int p = 0; p < 8; ++p) {
        float a = xv[p].x - mean, b = xv[p].y - mean;
        float c = xv[p].z - mean, d = xv[p].w - mean;
        q += (a * a + b * b) + (c * c + d * d);
    }
    q += __shfl_xor(q, 1); q += __shfl_xor(q, 2); q += __shfl_xor(q, 4);
    q += __shfl_xor(q, 8); q += __shfl_xor(q, 16);
    float inv = 1.0f / sqrtf(q * (1.f / 1024.f) + 1e-5f);
#pragma unroll
    for (int p = 0; p < 8; ++p) {
        int c0 = p * 128 + lr * 4;
        float4 gv = *(const float4*)(g + c0);
        float4 bv = *(const float4*)(be + c0);
        ushort4 o;
        o.x = f2bf((xv[p].x - mean) * inv * gv.x + bv.x);
        o.y = f2bf((xv[p].y - mean) * inv * gv.y + bv.y);
        o.z = f2bf((xv[p].z - mean) * inv * gv.z + bv.z);
        o.w = f2bf((xv[p].w - mean) * inv * gv.w + bv.w);
        *(ushort4*)(xo + (size_t)row * 1024 + c0) = o;
        *(ushort4*)&Tx[r][c0] = o;
    }
    __syncthreads();
    int w = tid >> 6, lane = tid & 63;
    int lrow = lane & 15, lk8 = (lane >> 4) * 8;
    f32x4 acc0 = {0.f, 0.f, 0.f, 0.f}, acc1 = {0.f, 0.f, 0.f, 0.f};
    const unsigned short* b0p = laT + (size_t)lrow * 1024 + w * 128 + lk8;
    const unsigned short* b1p = laT + (size_t)(16 + lrow) * 1024 + w * 128 + lk8;
#pragma unroll
    for (int kt = 0; kt < 128; kt += 32) {
        bf16x8 af = *(const bf16x8*)&Tx[lrow][w * 128 + kt + lk8];
        bf16x8 b0 = *(const bf16x8*)(b0p + kt);
        bf16x8 b1 = *(const bf16x8*)(b1p + kt);
        acc0 = __builtin_amdgcn_mfma_f32_16x16x32_bf16(af, b0, acc0, 0, 0, 0);
        acc1 = __builtin_amdgcn_mfma_f32_16x16x32_bf16(af, b1, acc1, 0, 0, 0);
    }
    red[0][w][lane] = acc0;
    red[1][w][lane] = acc1;
    __syncthreads();
    if (w == 0) {
        acc0 = ((red[0][0][lane] + red[0][1][lane]) + (red[0][2][lane] + red[0][3][lane]))
             + ((red[0][4][lane] + red[0][5][lane]) + (red[0][6][lane] + red[0][7][lane]));
        acc1 = ((red[1][0][lane] + red[1][1][lane]) + (red[1][2][lane] + red[1][3][lane]))
             + ((red[1][4][lane] + red[1][5][lane]) + (red[1][6][lane] + red[1][7][lane]));
        int lq = lane >> 4;
#pragma unroll
        for (int rg = 0; rg < 4; ++rg) {
            int orow = blockIdx.x * 16 + lq * 4 + rg;
            tmp[(size_t)orow * 64 + lrow] = f2bf(acc0[rg]);
            tmp[(size_t)orow * 64 + 16 + lrow] = f2bf(acc1[rg]);
            tmp[(size_t)orow * 64 + 32 + lrow] = 0;
            tmp[(size_t)orow * 64 + 48 + lrow] = 0;
        }
    }
}

// ---------------- LoRA-A via MFMA, 4-wave K-split (for ob / mb paths) ----------------
__global__ __launch_bounds__(256) void k_lora_mfma(const unsigned short* __restrict__ A,
        const unsigned short* __restrict__ laT, unsigned short* __restrict__ tmp, int K) {
    int rowBase = blockIdx.x * 16;
    int tid = threadIdx.x, w = tid >> 6, lane = tid & 63;
    int lrow = lane & 15, lk8 = (lane >> 4) * 8;
    int kq = K >> 2;
    f32x4 acc0 = {0.f, 0.f, 0.f, 0.f}, acc1 = {0.f, 0.f, 0.f, 0.f};
    const unsigned short* arow = A + (size_t)(rowBase + lrow) * K + w * kq + lk8;
    const unsigned short* b0p = laT + (size_t)lrow * K + w * kq + lk8;
    const unsigned short* b1p = laT + (size_t)(16 + lrow) * K + w * kq + lk8;
#pragma unroll 2
    for (int kt = 0; kt < kq; kt += 32) {
        bf16x8 af = *(const bf16x8*)(arow + kt);
        bf16x8 b0 = *(const bf16x8*)(b0p + kt);
        bf16x8 b1 = *(const bf16x8*)(b1p + kt);
        acc0 = __builtin_amdgcn_mfma_f32_16x16x32_bf16(af, b0, acc0, 0, 0, 0);
        acc1 = __builtin_amdgcn_mfma_f32_16x16x32_bf16(af, b1, acc1, 0, 0, 0);
    }
    __shared__ f32x4 red[2][4][64];
    red[0][w][lane] = acc0;
    red[1][w][lane] = acc1;
    __syncthreads();
    if (w == 0) {
        acc0 = red[0][0][lane] + red[0][1][lane] + red[0][2][lane] + red[0][3][lane];
        acc1 = red[1][0][lane] + red[1][1][lane] + red[1][2][lane] + red[1][3][lane];
        int lq = lane >> 4;
#pragma unroll
        for (int rg = 0; rg < 4; ++rg) {
            int row = rowBase + lq * 4 + rg;
            tmp[(size_t)row * 64 + lrow] = f2bf(acc0[rg]);
            tmp[(size_t)row * 64 + 16 + lrow] = f2bf(acc1[rg]);
            tmp[(size_t)row * 64 + 32 + lrow] = 0;
            tmp[(size_t)row * 64 + 48 + lrow] = 0;
        }
    }
}

// ---------------- batched weight prep (ALL layers, one launch): f32 [K][N] -> bf16 [N][K] ----------------
__global__ __launch_bounds__(256) void k_prep(
        const float* awB, const float* pwB, const float* fwB, const float* mwB,
        const float* albB, const float* plbB, const float* flbB, const float* mlbB,
        const float* alaB, const float* plaB, const float* flaB, const float* mlaB,
        unsigned short* WTqB, unsigned short* WTpB, unsigned short* WTfB, unsigned short* WTmB,
        unsigned short* LTqB, unsigned short* LTpB, unsigned short* LTfB, unsigned short* LTmB,
        unsigned short* LAqB, unsigned short* LApB, unsigned short* LAfB, unsigned short* LAmB) {
    int bid = blockIdx.x;
    size_t l = blockIdx.y;
    const float* src; unsigned short* dst; int K, N, ntn, local, dstS; float scale = 1.f;
    if      (bid < 768)  { src = awB + l*3145728;  dst = WTqB + l*3145728; K = 1024; N = 3072; ntn = 48; local = bid; dstS = K; }
    else if (bid < 1024) { src = pwB + l*1048576;  dst = WTpB + l*1048576; K = 1024; N = 1024; ntn = 16; local = bid - 768; dstS = K; }
    else if (bid < 2048) { src = fwB + l*4194304;  dst = WTfB + l*4194304; K = 1024; N = 4096; ntn = 64; local = bid - 1024; dstS = K; }
    else if (bid < 3072) { src = mwB + l*4194304;  dst = WTmB + l*4194304; K = 4096; N = 1024; ntn = 16; local = bid - 2048; dstS = K; }
    else if (bid < 3120) { src = albB + l*98304;   dst = LTqB + l*196608;  K = 32;   N = 3072; ntn = 48; local = bid - 3072; scale = 2.f; dstS = 64; }
    else if (bid < 3136) { src = plbB + l*32768;   dst = LTpB + l*65536;   K = 32;   N = 1024; ntn = 16; local = bid - 3120; scale = 2.f; dstS = 64; }
    else if (bid < 3200) { src = flbB + l*131072;  dst = LTfB + l*262144;  K = 32;   N = 4096; ntn = 64; local = bid - 3136; scale = 2.f; dstS = 64; }
    else if (bid < 3216) { src = mlbB + l*32768;   dst = LTmB + l*65536;   K = 32;   N = 1024; ntn = 16; local = bid - 3200; scale = 2.f; dstS = 64; }
    else if (bid < 3232) { src = alaB + l*32768;   dst = LAqB + l*32768;   K = 1024; N = 32;   ntn = 1;  local = bid - 3216; dstS = K; }
    else if (bid < 3248) { src = plaB + l*32768;   dst = LApB + l*32768;   K = 1024; N = 32;   ntn = 1;  local = bid - 3232; dstS = K; }
    else if (bid < 3264) { src = flaB + l*32768;   dst = LAfB + l*32768;   K = 1024; N = 32;   ntn = 1;  local = bid - 3248; dstS = K; }
    else                 { src = mlaB + l*131072;  dst = LAmB + l*131072;  K = 4096; N = 32;   ntn = 1;  local = bid - 3264; dstS = K; }
    int kt = local / ntn, nt = local % ntn;
    int k0 = kt * 64, n0 = nt * 64;
    __shared__ unsigned short Tl[64][66];
    int tid = threadIdx.x;
    int c4 = (tid & 15) * 4;
#pragma unroll
    for (int p = 0; p < 4; ++p) {
        int kl = p * 16 + (tid >> 4);
        if (k0 + kl < K && n0 + c4 < N) {
            float4 v = *(const float4*)(src + (size_t)(k0 + kl) * N + n0 + c4);
            ushort2 o0, o1;
            o0.x = f2bf(v.x * scale); o0.y = f2bf(v.y * scale);
            o1.x = f2bf(v.z * scale); o1.y = f2bf(v.w * scale);
            *(ushort2*)&Tl[kl][c4] = o0;
            *(ushort2*)&Tl[kl][c4 + 2] = o1;
        }
    }
    __syncthreads();
    int nl = tid >> 2;
    int kc = (tid & 3) * 8;
    if (n0 + nl < N) {
#pragma unroll
        for (int hh = 0; hh < 2; ++hh) {
            int kb = kc + hh * 32;
            if (k0 + kb < K) {
                unsigned short pk[8];
#pragma unroll
                for (int j = 0; j < 8; ++j) {
                    pk[j] = Tl[kb + j][nl];
                }
                *(uint4*)(dst + (size_t)(n0 + nl) * dstS + k0 + kb) = *(const uint4*)pk;
            } else if (k0 + kb < dstS) {
                uint4 z; z.x = 0; z.y = 0; z.z = 0; z.w = 0;
                *(uint4*)(dst + (size_t)(n0 + nl) * dstS + k0 + kb) = z;
            }
        }
    }
}

// ---------------- 128x128 8-phase GEMM (T2+T3+T4+T5, 4 waves) for proj / mproj ----------------
// EPI: 1 = +residual, write f32
template <int EPI>
__global__ __launch_bounds__(256, 1) void k_gemm128(
        const unsigned short* __restrict__ A, const unsigned short* __restrict__ WT,
        const float* __restrict__ bias, const unsigned short* __restrict__ tmpA,
        const unsigned short* __restrict__ lbT, const float* __restrict__ res,
        float* __restrict__ outF, int N, int K) {
    __shared__ unsigned short lds[9 * 4096];
    const int tid = threadIdx.x;
    const int wid = tid >> 6, lane = tid & 63;
    const int wr = wid >> 1, wc = wid & 1;          // 2x2 wave grid
    const int nBase = blockIdx.x * 128, rowBase = blockIdx.y * 128;
    const int nk = (K >> 6) + 1;                    // + LoRA K-tile

    f32x4 acc[4][4];
#pragma unroll
    for (int i = 0; i < 4; ++i)
#pragma unroll
        for (int j = 0; j < 4; ++j) acc[i][j] = f32x4{0.f, 0.f, 0.f, 0.f};

    auto stage = [&](int s) {
        int kt = s >> 2, part = s & 3;
        bool dead = kt >= nk;
        unsigned short* dst = &lds[(dead ? 8 : (s & 7)) * 4096];
        bool isA = part >= 2;
        int half = part & 1;
        bool lora = (kt == nk - 1);
#pragma unroll
        for (int i = 0; i < 2; ++i) {
            int o = ((i * 4 + wid) << 10) + (lane << 4);
            int r = o >> 7;
            int col = ((o & 127) ^ (((o >> 9) & 3) << 5)) >> 1;
            const unsigned short* src;
            if (dead) {
                src = A + (lane << 3);
            } else if (isA) {
                int grow = rowBase + half * 64 + r;
                src = lora ? tmpA + (size_t)grow * 64 + col
                           : A + (size_t)grow * K + kt * 64 + col;
            } else {
                int gcol = nBase + half * 64 + r;
                src = lora ? lbT + (size_t)gcol * 64 + col
                           : WT + (size_t)gcol * K + kt * 64 + col;
            }
            GL2LDS(src, dst + ((i * 4 + wid) << 9));
        }
    };

    stage(0); stage(1); stage(2); stage(3);
    stage(4); stage(5); stage(6);
    asm volatile("s_waitcnt vmcnt(6)" ::: "memory");
    __builtin_amdgcn_s_barrier();

    for (int kt = 0; kt < nk; ++kt) {
        const unsigned short* aPart = &lds[(((kt & 1) << 2) + 2 + wr) * 4096];
        const unsigned short* bPart = &lds[(((kt & 1) << 2) + wc) * 4096];
        bf16x8 bfr[4][2];
#pragma unroll
        for (int p = 0; p < 4; ++p) {
            bf16x8 af[2];
#pragma unroll
            for (int kk = 0; kk < 2; ++kk) {
                int row = p * 16 + (lane & 15);
                int cb = (kk * 64 + ((lane >> 4) << 4)) ^ (((row >> 2) & 3) << 5);
                af[kk] = *(const bf16x8*)&aPart[row * 64 + (cb >> 1)];
            }
            if (p == 0) {
#pragma unroll
                for (int n = 0; n < 4; ++n)
#pragma unroll
                    for (int kk = 0; kk < 2; ++kk) {
                        int row = n * 16 + (lane & 15);
                        int cb = (kk * 64 + ((lane >> 4) << 4)) ^ (((row >> 2) & 3) << 5);
                        bfr[n][kk] = *(const bf16x8*)&bPart[row * 64 + (cb >> 1)];
                    }
            }
            stage(p == 0 ? 4 * (kt + 1) + 3 : 4 * (kt + 2) + (p - 1));
            __builtin_amdgcn_s_barrier();
            __builtin_amdgcn_s_setprio(1);
#pragma unroll
            for (int n = 0; n < 4; ++n)
#pragma unroll
                for (int kk = 0; kk < 2; ++kk)
                    acc[p][n] = __builtin_amdgcn_mfma_f32_16x16x32_bf16(
                        af[kk], bfr[n][kk], acc[p][n], 0, 0, 0);
            __builtin_amdgcn_s_setprio(0);
            if (p == 3) asm volatile("s_waitcnt vmcnt(6)" ::: "memory");
            __builtin_amdgcn_s_barrier();
        }
    }

#pragma unroll
    for (int n = 0; n < 4; ++n) {
        int col = nBase + wc * 64 + n * 16 + (lane & 15);
        float bv = bias[col];
#pragma unroll
        for (int m = 0; m < 4; ++m) {
            int row0 = rowBase + wr * 64 + m * 16 + ((lane >> 4) << 2);
#pragma unroll
            for (int rg = 0; rg < 4; ++rg) {
                int row = row0 + rg;
                float v = acc[m][n][rg] + bv;
                size_t idx = (size_t)row * N + col;
                if (EPI == 1) v += res[idx];
                outF[idx] = v;
            }
        }
    }
}

// ---------------- 256x256 8-phase GEMM (T2+T3+T4+T5) for qkv / fc ----------------
// EPI: 2 = GELU, write bf16 ; 3 = fused head-split + KV fake-quant -> qh/kh/vh
template <int EPI>
__global__ __launch_bounds__(512, 1) void k_gemm256(
        const unsigned short* __restrict__ A, const unsigned short* __restrict__ WT,
        const float* __restrict__ bias, const unsigned short* __restrict__ tmpA,
        const unsigned short* __restrict__ lbT,
        const float* __restrict__ kvmin, const float* __restrict__ kvmax, int layer,
        unsigned short* __restrict__ qh, unsigned short* __restrict__ kh,
        unsigned short* __restrict__ vh,
        float* __restrict__ outF, unsigned short* __restrict__ outH, int N, int K) {
    __shared__ unsigned short lds[9 * 8192];
    const int tid = threadIdx.x;
    const int wid = tid >> 6, lane = tid & 63;
    const int wr = wid >> 2, wc = wid & 3;          // 2x4 wave grid
    const int nBase = blockIdx.x * 256, rowBase = blockIdx.y * 256;
    const int nk = (K >> 6) + 1;                    // + LoRA K-tile

    f32x4 acc[8][4];
#pragma unroll
    for (int i = 0; i < 8; ++i)
#pragma unroll
        for (int j = 0; j < 4; ++j) acc[i][j] = f32x4{0.f, 0.f, 0.f, 0.f};

    auto stage = [&](int s) {
        int kt = s >> 2, part = s & 3;
        bool dead = kt >= nk;
        unsigned short* dst = &lds[(dead ? 8 : (s & 7)) * 8192];
        bool isA = part >= 2;
        int half = part & 1;
        bool lora = (kt == nk - 1);
#pragma unroll
        for (int i = 0; i < 2; ++i) {
            int o = ((i * 8 + wid) << 10) + (lane << 4);
            int r = o >> 7;
            int col = ((o & 127) ^ (((o >> 9) & 3) << 5)) >> 1;
            const unsigned short* src;
            if (dead) {
                src = A + (lane << 3);
            } else if (isA) {
                int grow = rowBase + half * 128 + r;
                src = lora ? tmpA + (size_t)grow * 64 + col
                           : A + (size_t)grow * K + kt * 64 + col;
            } else {
                int gcol = nBase + half * 128 + r;
                src = lora ? lbT + (size_t)gcol * 64 + col
                           : WT + (size_t)gcol * K + kt * 64 + col;
            }
            GL2LDS(src, dst + ((i * 8 + wid) << 9));
        }
    };

    stage(0); stage(1); stage(2); stage(3);
    stage(4); stage(5); stage(6);
    asm volatile("s_waitcnt vmcnt(6)" ::: "memory");
    __builtin_amdgcn_s_barrier();

    for (int kt = 0; kt < nk; ++kt) {
        const unsigned short* aPart = &lds[(((kt & 1) << 2) + 2 + wr) * 8192];
        const unsigned short* bPart = &lds[(((kt & 1) << 2) + (wc >> 1)) * 8192];
        bf16x8 bfr[4][2];
#pragma unroll
        for (int p = 0; p < 4; ++p) {
            bf16x8 af[2][2];
#pragma unroll
            for (int mm = 0; mm < 2; ++mm)
#pragma unroll
                for (int kk = 0; kk < 2; ++kk) {
                    int row = (p * 2 + mm) * 16 + (lane & 15);
                    int cb = (kk * 64 + ((lane >> 4) << 4)) ^ (((row >> 2) & 3) << 5);
                    af[mm][kk] = *(const bf16x8*)&aPart[row * 64 + (cb >> 1)];
                }
            if (p == 0) {
#pragma unroll
                for (int n = 0; n < 4; ++n)
#pragma unroll
                    for (int kk = 0; kk < 2; ++kk) {
                        int row = ((wc & 1) << 6) + n * 16 + (lane & 15);
                        int cb = (kk * 64 + ((lane >> 4) << 4)) ^ (((row >> 2) & 3) << 5);
                        bfr[n][kk] = *(const bf16x8*)&bPart[row * 64 + (cb >> 1)];
                    }
            }
            stage(p == 0 ? 4 * (kt + 1) + 3 : 4 * (kt + 2) + (p - 1));
            __builtin_amdgcn_s_barrier();
            __builtin_amdgcn_s_setprio(1);
#pragma unroll
            for (int mm = 0; mm < 2; ++mm)
#pragma unroll
                for (int n = 0; n < 4; ++n)
#pragma unroll
                    for (int kk = 0; kk < 2; ++kk)
                        acc[p * 2 + mm][n] = __builtin_amdgcn_mfma_f32_16x16x32_bf16(
                            af[mm][kk], bfr[n][kk], acc[p * 2 + mm][n], 0, 0, 0);
            __builtin_amdgcn_s_setprio(0);
            if (p == 3) asm volatile("s_waitcnt vmcnt(6)" ::: "memory");
            __builtin_amdgcn_s_barrier();
        }
    }

    if (EPI == 3) {
        const int b = rowBase >> 10, t0 = rowBase & 1023;
        const int sec = nBase >> 10, nb = nBase & 1023;
        const int lrow = lane & 15, lq4 = (lane >> 4) << 2;
        float qs = 1.f, qzp = 0.f, qinv = 1.f;
        if (sec) {
            float mnv = kvmin[layer], mxv = kvmax[layer];
            qs = (mxv - mnv) * (1.f / 255.f);
            qzp = rintf(-mnv / qs);
            qinv = 1.f / qs;
        }
#pragma unroll
        for (int n = 0; n < 4; ++n) {
            int dd = wc * 64 + n * 16 + lrow;
            float bv = bias[nBase + dd];
#pragma unroll
            for (int m = 0; m < 8; ++m) {
#pragma unroll
                for (int rg = 0; rg < 4; ++rg) {
                    int tt = wr * 128 + m * 16 + lq4 + rg;
                    float v = acc[m][n][rg] + bv;
                    if (sec) {
                        float qv = rintf(v * qinv) + qzp;
                        qv = fminf(fmaxf(qv, 0.f), 255.f);
                        v = (qv - qzp) * qs;
                    }
                    int r = (sec == 2) ? dd : tt;
                    int c = (sec == 2) ? tt : dd;
                    lds[r * 256 + (c ^ ((r & 7) << 3))] = f2bf(v);
                }
            }
        }
        __syncthreads();
        if (sec < 2) {
            unsigned short* dstp = sec ? kh : qh;
            int tL = tid & 255;
            int hp = tid >> 8;
#pragma unroll
            for (int hi = 0; hi < 2; ++hi) {
                int dL = (hp * 2 + hi) * 64;
                int hh = (nb >> 6) + hp * 2 + hi;
                size_t base = (((size_t)(b * 16 + hh)) * 1024 + t0 + tL) * 64;
#pragma unroll
                for (int j = 0; j < 8; ++j) {
                    int c = (dL + j * 8) ^ ((tL & 7) << 3);
                    *(uint4*)(dstp + base + j * 8) = *(const uint4*)&lds[tL * 256 + c];
                }
            }
        } else {
            int dL = tid & 255;
            int th = (tid >> 8) * 128;
            int hh = (nb >> 6) + (dL >> 6);
            size_t base = (((size_t)(b * 16 + hh)) * 64 + (dL & 63)) * 1024 + t0 + th;
#pragma unroll
            for (int j = 0; j < 16; ++j) {
                int c = (th + j * 8) ^ ((dL & 7) << 3);
                *(uint4*)(vh + base + j * 8) = *(const uint4*)&lds[dL * 256 + c];
            }
        }
    } else {
#pragma unroll
        for (int n = 0; n < 4; ++n) {
            int col = nBase + wc * 64 + n * 16 + (lane & 15);
            float bv = bias[col];
#pragma unroll
            for (int m = 0; m < 8; ++m) {
                int row0 = rowBase + wr * 128 + m * 16 + ((lane >> 4) << 2);
#pragma unroll
                for (int rg = 0; rg < 4; ++rg) {
                    int row = row0 + rg;
                    float v = acc[m][n][rg] + bv;
                    size_t idx = (size_t)row * N + col;
                    v = 0.5f * v * (1.f + erff(v * 0.70710678118654752f));
                    outH[idx] = f2bf(v);
                }
            }
        }
    }
}

// ---------------- flash attention (causal), 64 q-rows/block, 4 waves ----------------
// swapped QK^T; tree reductions for max/sum (max exact; sum reassociated, drift ~1e-7)
__global__ __launch_bounds__(256) void k_attn(const unsigned short* __restrict__ qh,
        const unsigned short* __restrict__ kh, const unsigned short* __restrict__ vh,
        unsigned short* __restrict__ o) {
    int fid = blockIdx.y * 16 + blockIdx.x;
    int wgid = (fid & 7) * 128 + (fid >> 3);
    int bh = wgid >> 4, qb = wgid & 15;
    int b = bh >> 4, hh = bh & 15;
    int tid = threadIdx.x, w = tid >> 6, lane = tid & 63;
    int cq = lane & 15;
    int g = lane >> 4;
    int lk8 = g * 8;
    __shared__ unsigned short Kl[64][72];
    __shared__ unsigned short Vt[64][72];
    __shared__ unsigned short Pl[4][16][72];
    const float SCL = 0.18033688011112042f;   // 0.125 * log2(e)
    int qrow = qb * 64 + w * 16 + cq;
    bf16x8 aq[2];
    aq[0] = *(const bf16x8*)(qh + ((size_t)bh * 1024 + qrow) * 64 + lk8);
    aq[1] = *(const bf16x8*)(qh + ((size_t)bh * 1024 + qrow) * 64 + 32 + lk8);
    f32x4 od[4];
#pragma unroll
    for (int i = 0; i < 4; ++i) od[i] = f32x4{0.f, 0.f, 0.f, 0.f};
    float mrun = -3e38f, lrun = 0.f;
    int rl = tid >> 2, seg = (tid & 3) * 16;
    for (int kb = 0; kb <= qb; ++kb) {
        __syncthreads();
        {
            size_t kbase = ((size_t)bh * 1024 + kb * 64 + rl) * 64 + seg;
            *(uint4*)&Kl[rl][seg] = *(const uint4*)(kh + kbase);
            *(uint4*)&Kl[rl][seg + 8] = *(const uint4*)(kh + kbase + 8);
            size_t vbase = ((size_t)bh * 64 + rl) * 1024 + kb * 64 + seg;
            *(uint4*)&Vt[rl][seg] = *(const uint4*)(vh + vbase);
            *(uint4*)&Vt[rl][seg + 8] = *(const uint4*)(vh + vbase + 8);
        }
        __syncthreads();
        f32x4 st[4];
#pragma unroll
        for (int ktile = 0; ktile < 4; ++ktile) {
            f32x4 sacc = f32x4{0.f, 0.f, 0.f, 0.f};
#pragma unroll
            for (int dh = 0; dh < 2; ++dh) {
                bf16x8 bk = *(const bf16x8*)&Kl[ktile * 16 + cq][dh * 32 + lk8];
                sacc = __builtin_amdgcn_mfma_f32_16x16x32_bf16(bk, aq[dh], sacc, 0, 0, 0);
            }
            st[ktile] = sacc * SCL;
        }
        if (kb == qb) {
#pragma unroll
            for (int ktile = 0; ktile < 4; ++ktile) {
#pragma unroll
                for (int rg = 0; rg < 4; ++rg) {
                    int kidx = kb * 64 + ktile * 16 + g * 4 + rg;
                    if (kidx > qrow) st[ktile][rg] = -3e38f;
                }
            }
        }
        // tree max (exact) + tree sum (reassociated)
        float tm[4];
#pragma unroll
        for (int ktile = 0; ktile < 4; ++ktile)
            tm[ktile] = fmaxf(fmaxf(st[ktile][0], st[ktile][1]),
                              fmaxf(st[ktile][2], st[ktile][3]));
        float pmax = fmaxf(fmaxf(tm[0], tm[1]), fmaxf(tm[2], tm[3]));
        pmax = fmaxf(pmax, __shfl_xor(pmax, 16));
        pmax = fmaxf(pmax, __shfl_xor(pmax, 32));
        float mnew = fmaxf(mrun, pmax);
#pragma unroll
        for (int ktile = 0; ktile < 4; ++ktile)
#pragma unroll
            for (int rg = 0; rg < 4; ++rg)
                st[ktile][rg] = exp2f(st[ktile][rg] - mnew);
        float ts[4];
#pragma unroll
        for (int ktile = 0; ktile < 4; ++ktile)
            ts[ktile] = (st[ktile][0] + st[ktile][1]) + (st[ktile][2] + st[ktile][3]);
        float sum = (ts[0] + ts[1]) + (ts[2] + ts[3]);
        sum += __shfl_xor(sum, 16);
        sum += __shfl_xor(sum, 32);
        float corr = exp2f(mrun - mnew);
        lrun = lrun * corr + sum;
        mrun = mnew;
#pragma unroll
        for (int rg = 0; rg < 4; ++rg) {
            float cv = __shfl(corr, (lane & 48) | (g * 4 + rg));
#pragma unroll
            for (int dt = 0; dt < 4; ++dt) od[dt][rg] *= cv;
        }
#pragma unroll
        for (int ktile = 0; ktile < 4; ++ktile) {
            ushort4 pw;
            pw.x = f2bf(st[ktile][0]); pw.y = f2bf(st[ktile][1]);
            pw.z = f2bf(st[ktile][2]); pw.w = f2bf(st[ktile][3]);
            *(ushort4*)&Pl[w][cq][ktile * 16 + g * 4] = pw;
        }
        bf16x8 pa[2];
        pa[0] = *(const bf16x8*)&Pl[w][cq][lk8];
        pa[1] = *(const bf16x8*)&Pl[w][cq][32 + lk8];
#pragma unroll
        for (int dt = 0; dt < 4; ++dt) {
#pragma unroll
            for (int kh2 = 0; kh2 < 2; ++kh2) {
                bf16x8 bv = *(const bf16x8*)&Vt[dt * 16 + cq][kh2 * 32 + lk8];
                od[dt] = __builtin_amdgcn_mfma_f32_16x16x32_bf16(pa[kh2], bv, od[dt], 0, 0, 0);
            }
        }
    }
#pragma unroll
    for (int rg = 0; rg < 4; ++rg) {
        float lv = __shfl(lrun, (lane & 48) | (g * 4 + rg));
        float inv = 1.0f / lv;
        int row = qb * 64 + w * 16 + g * 4 + rg;
#pragma unroll
        for (int dt = 0; dt < 4; ++dt) {
            float val = od[dt][rg] * inv;
            o[((size_t)(b * 1024 + row)) * 1024 + hh * 64 + dt * 16 + cq] = f2bf(val);
        }
    }
}

// ---------------- host orchestration ----------------
extern "C" void kernel_launch(void* const* d_in, const int* in_sizes, int n_in,
                              void* d_out, int out_size, void* d_ws, size_t ws_size,
                              hipStream_t stream) {
    const int*   ids      = (const int*)d_in[0];
    const float* wte      = (const float*)d_in[1];
    const float* wpe      = (const float*)d_in[2];
    const float* ln1_g    = (const float*)d_in[3];
    const float* ln1_b    = (const float*)d_in[4];
    const float* attn_w   = (const float*)d_in[5];
    const float* attn_b   = (const float*)d_in[6];
    const float* attn_la  = (const float*)d_in[7];
    const float* attn_lb  = (const float*)d_in[8];
    const float* proj_w   = (const float*)d_in[9];
    const float* proj_b   = (const float*)d_in[10];
    const float* proj_la  = (const float*)d_in[11];
    const float* proj_lb  = (const float*)d_in[12];
    const float* ln2_g    = (const float*)d_in[13];
    const float* ln2_b    = (const float*)d_in[14];
    const float* fc_w     = (const float*)d_in[15];
    const float* fc_b     = (const float*)d_in[16];
    const float* fc_la    = (const float*)d_in[17];
    const float* fc_lb    = (const float*)d_in[18];
    const float* mproj_w  = (const float*)d_in[19];
    const float* mproj_b  = (const float*)d_in[20];
    const float* mproj_la = (const float*)d_in[21];
    const float* mproj_lb = (const float*)d_in[22];
    const float* kv_min   = (const float*)d_in[23];
    const float* kv_max   = (const float*)d_in[24];
    const float* lnf_g    = (const float*)d_in[25];
    const float* lnf_b    = (const float*)d_in[26];

    char* ws = (char*)d_ws;
    size_t off = 0;
    auto alloc = [&](size_t bytes) -> char* {
        char* p = ws + off;
        off = (off + bytes + 255) & ~(size_t)255;
        return p;
    };
    float*          h   = (float*)alloc(4096ull * 1024 * 4);
    unsigned short* xb  = (unsigned short*)alloc(4096ull * 1024 * 2);
    unsigned short* tmp = (unsigned short*)alloc(4096ull * 64 * 2);
    unsigned short* qhb = (unsigned short*)alloc(64ull * 1024 * 64 * 2);
    unsigned short* khb = (unsigned short*)alloc(64ull * 1024 * 64 * 2);
    unsigned short* vhb = (unsigned short*)alloc(64ull * 64 * 1024 * 2);
    unsigned short* ob  = (unsigned short*)alloc(4096ull * 1024 * 2);
    unsigned short* mb  = (unsigned short*)alloc(4096ull * 4096 * 2);
    unsigned short* WTq = (unsigned short*)alloc(12ull * 3072 * 1024 * 2);
    unsigned short* WTp = (unsigned short*)alloc(12ull * 1024 * 1024 * 2);
    unsigned short* WTf = (unsigned short*)alloc(12ull * 4096 * 1024 * 2);
    unsigned short* WTm = (unsigned short*)alloc(12ull * 1024 * 4096 * 2);
    unsigned short* LTq = (unsigned short*)alloc(12ull * 3072 * 64 * 2);
    unsigned short* LTp = (unsigned short*)alloc(12ull * 1024 * 64 * 2);
    unsigned short* LTf = (unsigned short*)alloc(12ull * 4096 * 64 * 2);
    unsigned short* LTm = (unsigned short*)alloc(12ull * 1024 * 64 * 2);
    unsigned short* LAq = (unsigned short*)alloc(12ull * 32 * 1024 * 2);
    unsigned short* LAp = (unsigned short*)alloc(12ull * 32 * 1024 * 2);
    unsigned short* LAf = (unsigned short*)alloc(12ull * 32 * 1024 * 2);
    unsigned short* LAm = (unsigned short*)alloc(12ull * 32 * 4096 * 2);

    k_embed<<<4096, 256, 0, stream>>>(ids, wte, wpe, h);
    k_prep<<<dim3(3328, 12), 256, 0, stream>>>(
        attn_w, proj_w, fc_w, mproj_w,
        attn_lb, proj_lb, fc_lb, mproj_lb,
        attn_la, proj_la, fc_la, mproj_la,
        WTq, WTp, WTf, WTm, LTq, LTp, LTf, LTm, LAq, LAp, LAf, LAm);
    for (int l = 0; l < 12; ++l) {
        k_ln_lora<<<256, 512, 0, stream>>>(h, ln1_g + l * 1024, ln1_b + l * 1024,
                                           LAq + (size_t)l * 32768, xb, tmp);
        k_gemm256<3><<<dim3(12, 16), 512, 0, stream>>>(xb, WTq + (size_t)l * 3145728,
                                                       attn_b + l * 3072, tmp, LTq + (size_t)l * 196608,
                                                       kv_min, kv_max, l, qhb, khb, vhb,
                                                       nullptr, nullptr, 3072, 1024);
        k_attn<<<dim3(16, 64), 256, 0, stream>>>(qhb, khb, vhb, ob);
        k_lora_mfma<<<256, 256, 0, stream>>>(ob, LAp + (size_t)l * 32768, tmp, 1024);
        k_gemm128<1><<<dim3(8, 32), 256, 0, stream>>>(ob, WTp + (size_t)l * 1048576,
                                                      proj_b + l * 1024, tmp, LTp + (size_t)l * 65536,
                                                      h, h, 1024, 1024);
        k_ln_lora<<<256, 512, 0, stream>>>(h, ln2_g + l * 1024, ln2_b + l * 1024,
                                           LAf + (size_t)l * 32768, xb, tmp);
        k_gemm256<2><<<dim3(16, 16), 512, 0, stream>>>(xb, WTf + (size_t)l * 4194304,
                                                       fc_b + l * 4096, tmp, LTf + (size_t)l * 262144,
                                                       nullptr, nullptr, 0, nullptr, nullptr, nullptr,
                                                       nullptr, mb, 4096, 1024);
        k_lora_mfma<<<256, 256, 0, stream>>>(mb, LAm + (size_t)l * 131072, tmp, 4096);
        k_gemm128<1><<<dim3(8, 32), 256, 0, stream>>>(mb, WTm + (size_t)l * 4194304,
                                                      mproj_b + l * 1024, tmp, LTm + (size_t)l * 65536,
                                                      h, h, 1024, 4096);
    }
    k_lnf<<<4096, 256, 0, stream>>>(h, lnf_g, lnf_b, (float*)d_out);
}

// Round 18
// 3544.124 us; speedup vs baseline: 1.0451x; 1.0016x over previous
//
#include <hip/hip_runtime.h>
#include <hip/hip_bf16.h>

// 12-layer GPT2-ish forward with LoRA + KV fake-quant, bf16 MFMA internals.
// B=4 T=1024 D=1024 H=16 HD=64 L=12 R=32, SCALING=2.0, EPS=1e-5, QMAX=255.
// (R15 configuration: best measured passing build.)

typedef __bf16 bf16x8 __attribute__((ext_vector_type(8)));
typedef float f32x4 __attribute__((ext_vector_type(4)));

static __device__ __forceinline__ float bf2f(unsigned short u) {
    union { unsigned int i; float f; } c; c.i = ((unsigned int)u) << 16; return c.f;
}
static __device__ __forceinline__ unsigned short f2bf(float f) {
    unsigned int u = __float_as_uint(f);
    u += 0x7fffu + ((u >> 16) & 1u);   // RNE
    return (unsigned short)(u >> 16);
}

// async global->LDS, 16B per lane; LDS dst must be wave-uniform (HW adds lane*16B)
#define GL2LDS(g, l) __builtin_amdgcn_global_load_lds( \
    (const __attribute__((address_space(1))) unsigned int*)(g), \
    (__attribute__((address_space(3))) unsigned int*)(l), 16, 0, 0)

// ---------------- embedding ----------------
__global__ __launch_bounds__(256) void k_embed(const int* __restrict__ ids,
        const float* __restrict__ wte, const float* __restrict__ wpe,
        float* __restrict__ h) {
    int row = blockIdx.x;          // b*1024 + t
    int t = row & 1023;
    int id = ids[row];
    int d = threadIdx.x * 4;
    float4 a = *(const float4*)(wte + (size_t)id * 1024 + d);
    float4 b = *(const float4*)(wpe + (size_t)t * 1024 + d);
    float4 o = make_float4(a.x + b.x, a.y + b.y, a.z + b.z, a.w + b.w);
    *(float4*)(h + (size_t)row * 1024 + d) = o;
}

// ---------------- layernorm (final, f32 out) ----------------
__global__ __launch_bounds__(256) void k_lnf(const float* __restrict__ h,
        const float* __restrict__ g, const float* __restrict__ be,
        float* __restrict__ fo) {
    int row = blockIdx.x, tid = threadIdx.x;
    float4 v = *(const float4*)(h + (size_t)row * 1024 + tid * 4);
    float s = v.x + v.y + v.z + v.w;
    for (int off = 32; off; off >>= 1) s += __shfl_down(s, off);
    __shared__ float red[8];
    int wid = tid >> 6, lane = tid & 63;
    if (!lane) red[wid] = s;
    __syncthreads();
    float mean = (red[0] + red[1] + red[2] + red[3]) * (1.f / 1024.f);
    float dx = v.x - mean, dy = v.y - mean, dz = v.z - mean, dw = v.w - mean;
    float q = dx * dx + dy * dy + dz * dz + dw * dw;
    for (int off = 32; off; off >>= 1) q += __shfl_down(q, off);
    if (!lane) red[4 + wid] = q;
    __syncthreads();
    float var = (red[4] + red[5] + red[6] + red[7]) * (1.f / 1024.f);
    float inv = 1.0f / sqrtf(var + 1e-5f);
    float4 gv = *(const float4*)(g + tid * 4);
    float4 bv = *(const float4*)(be + tid * 4);
    *(float4*)(fo + (size_t)row * 1024 + tid * 4) = make_float4(
        dx * inv * gv.x + bv.x, dy * inv * gv.y + bv.y,
        dz * inv * gv.z + bv.z, dw * inv * gv.w + bv.w);
}

// ---------------- fused LN + LoRA-A: xb = bf16(LN(h)); tmp = bf16(xb @ laT^T) ----------------
__global__ __launch_bounds__(512) void k_ln_lora(const float* __restrict__ h,
        const float* __restrict__ g, const float* __restrict__ be,
        const unsigned short* __restrict__ laT,
        unsigned short* __restrict__ xo, unsigned short* __restrict__ tmp) {
    __shared__ __align__(16) unsigned short Tx[16][1032];
    __shared__ f32x4 red[2][8][64];
    int tid = threadIdx.x;
    int r = tid >> 5;            // local row 0..15
    int lr = tid & 31;           // lane-in-row
    int row = blockIdx.x * 16 + r;
    const float* hrow = h + (size_t)row * 1024;
    float4 xv[8];
    float s = 0.f;
#pragma unroll
    for (int p = 0; p < 8; ++p) {
        xv[p] = *(const float4*)(hrow + p * 128 + lr * 4);
        s += (xv[p].x + xv[p].y) + (xv[p].z + xv[p].w);
    }
    s += __shfl_xor(s, 1); s += __shfl_xor(s, 2); s += __shfl_xor(s, 4);
    s += __shfl_xor(s, 8); s += __shfl_xor(s, 16);
    float mean = s * (1.f / 1024.f);
    float q = 0.f;
#pragma unroll
    for (int p = 0; p < 8; ++p) {
        float a = xv[p].x - mean, b = xv[p].y - mean;
        float c = xv[p].z - mean, d = xv[p].w - mean;
        q += (a * a + b * b) + (c * c + d * d);
    }
    q += __shfl_xor(q, 1); q += __shfl_xor(q, 2); q += __shfl_xor(q, 4);
    q += __shfl_xor(q, 8); q += __shfl_xor(q, 16);
    float inv = 1.0f / sqrtf(q * (1.f / 1024.f) + 1e-5f);
#pragma unroll
    for (int p = 0; p < 8; ++p) {
        int c0 = p * 128 + lr * 4;
        float4 gv = *(const float4*)(g + c0);
        float4 bv = *(const float4*)(be + c0);
        ushort4 o;
        o.x = f2bf((xv[p].x - mean) * inv * gv.x + bv.x);
        o.y = f2bf((xv[p].y - mean) * inv * gv.y + bv.y);
        o.z = f2bf((xv[p].z - mean) * inv * gv.z + bv.z);
        o.w = f2bf((xv[p].w - mean) * inv * gv.w + bv.w);
        *(ushort4*)(xo + (size_t)row * 1024 + c0) = o;
        *(ushort4*)&Tx[r][c0] = o;
    }
    __syncthreads();
    int w = tid >> 6, lane = tid & 63;
    int lrow = lane & 15, lk8 = (lane >> 4) * 8;
    f32x4 acc0 = {0.f, 0.f, 0.f, 0.f}, acc1 = {0.f, 0.f, 0.f, 0.f};
    const unsigned short* b0p = laT + (size_t)lrow * 1024 + w * 128 + lk8;
    const unsigned short* b1p = laT + (size_t)(16 + lrow) * 1024 + w * 128 + lk8;
#pragma unroll
    for (int kt = 0; kt < 128; kt += 32) {
        bf16x8 af = *(const bf16x8*)&Tx[lrow][w * 128 + kt + lk8];
        bf16x8 b0 = *(const bf16x8*)(b0p + kt);
        bf16x8 b1 = *(const bf16x8*)(b1p + kt);
        acc0 = __builtin_amdgcn_mfma_f32_16x16x32_bf16(af, b0, acc0, 0, 0, 0);
        acc1 = __builtin_amdgcn_mfma_f32_16x16x32_bf16(af, b1, acc1, 0, 0, 0);
    }
    red[0][w][lane] = acc0;
    red[1][w][lane] = acc1;
    __syncthreads();
    if (w == 0) {
        acc0 = ((red[0][0][lane] + red[0][1][lane]) + (red[0][2][lane] + red[0][3][lane]))
             + ((red[0][4][lane] + red[0][5][lane]) + (red[0][6][lane] + red[0][7][lane]));
        acc1 = ((red[1][0][lane] + red[1][1][lane]) + (red[1][2][lane] + red[1][3][lane]))
             + ((red[1][4][lane] + red[1][5][lane]) + (red[1][6][lane] + red[1][7][lane]));
        int lq = lane >> 4;
#pragma unroll
        for (int rg = 0; rg < 4; ++rg) {
            int orow = blockIdx.x * 16 + lq * 4 + rg;
            tmp[(size_t)orow * 64 + lrow] = f2bf(acc0[rg]);
            tmp[(size_t)orow * 64 + 16 + lrow] = f2bf(acc1[rg]);
            tmp[(size_t)orow * 64 + 32 + lrow] = 0;
            tmp[(size_t)orow * 64 + 48 + lrow] = 0;
        }
    }
}

// ---------------- LoRA-A via MFMA, 4-wave K-split (for ob / mb paths) ----------------
__global__ __launch_bounds__(256) void k_lora_mfma(const unsigned short* __restrict__ A,
        const unsigned short* __restrict__ laT, unsigned short* __restrict__ tmp, int K) {
    int rowBase = blockIdx.x * 16;
    int tid = threadIdx.x, w = tid >> 6, lane = tid & 63;
    int lrow = lane & 15, lk8 = (lane >> 4) * 8;
    int kq = K >> 2;
    f32x4 acc0 = {0.f, 0.f, 0.f, 0.f}, acc1 = {0.f, 0.f, 0.f, 0.f};
    const unsigned short* arow = A + (size_t)(rowBase + lrow) * K + w * kq + lk8;
    const unsigned short* b0p = laT + (size_t)lrow * K + w * kq + lk8;
    const unsigned short* b1p = laT + (size_t)(16 + lrow) * K + w * kq + lk8;
#pragma unroll 2
    for (int kt = 0; kt < kq; kt += 32) {
        bf16x8 af = *(const bf16x8*)(arow + kt);
        bf16x8 b0 = *(const bf16x8*)(b0p + kt);
        bf16x8 b1 = *(const bf16x8*)(b1p + kt);
        acc0 = __builtin_amdgcn_mfma_f32_16x16x32_bf16(af, b0, acc0, 0, 0, 0);
        acc1 = __builtin_amdgcn_mfma_f32_16x16x32_bf16(af, b1, acc1, 0, 0, 0);
    }
    __shared__ f32x4 red[2][4][64];
    red[0][w][lane] = acc0;
    red[1][w][lane] = acc1;
    __syncthreads();
    if (w == 0) {
        acc0 = red[0][0][lane] + red[0][1][lane] + red[0][2][lane] + red[0][3][lane];
        acc1 = red[1][0][lane] + red[1][1][lane] + red[1][2][lane] + red[1][3][lane];
        int lq = lane >> 4;
#pragma unroll
        for (int rg = 0; rg < 4; ++rg) {
            int row = rowBase + lq * 4 + rg;
            tmp[(size_t)row * 64 + lrow] = f2bf(acc0[rg]);
            tmp[(size_t)row * 64 + 16 + lrow] = f2bf(acc1[rg]);
            tmp[(size_t)row * 64 + 32 + lrow] = 0;
            tmp[(size_t)row * 64 + 48 + lrow] = 0;
        }
    }
}

// ---------------- batched weight prep (ALL layers, one launch): f32 [K][N] -> bf16 [N][K] ----------------
__global__ __launch_bounds__(256) void k_prep(
        const float* awB, const float* pwB, const float* fwB, const float* mwB,
        const float* albB, const float* plbB, const float* flbB, const float* mlbB,
        const float* alaB, const float* plaB, const float* flaB, const float* mlaB,
        unsigned short* WTqB, unsigned short* WTpB, unsigned short* WTfB, unsigned short* WTmB,
        unsigned short* LTqB, unsigned short* LTpB, unsigned short* LTfB, unsigned short* LTmB,
        unsigned short* LAqB, unsigned short* LApB, unsigned short* LAfB, unsigned short* LAmB) {
    int bid = blockIdx.x;
    size_t l = blockIdx.y;
    const float* src; unsigned short* dst; int K, N, ntn, local, dstS; float scale = 1.f;
    if      (bid < 768)  { src = awB + l*3145728;  dst = WTqB + l*3145728; K = 1024; N = 3072; ntn = 48; local = bid; dstS = K; }
    else if (bid < 1024) { src = pwB + l*1048576;  dst = WTpB + l*1048576; K = 1024; N = 1024; ntn = 16; local = bid - 768; dstS = K; }
    else if (bid < 2048) { src = fwB + l*4194304;  dst = WTfB + l*4194304; K = 1024; N = 4096; ntn = 64; local = bid - 1024; dstS = K; }
    else if (bid < 3072) { src = mwB + l*4194304;  dst = WTmB + l*4194304; K = 4096; N = 1024; ntn = 16; local = bid - 2048; dstS = K; }
    else if (bid < 3120) { src = albB + l*98304;   dst = LTqB + l*196608;  K = 32;   N = 3072; ntn = 48; local = bid - 3072; scale = 2.f; dstS = 64; }
    else if (bid < 3136) { src = plbB + l*32768;   dst = LTpB + l*65536;   K = 32;   N = 1024; ntn = 16; local = bid - 3120; scale = 2.f; dstS = 64; }
    else if (bid < 3200) { src = flbB + l*131072;  dst = LTfB + l*262144;  K = 32;   N = 4096; ntn = 64; local = bid - 3136; scale = 2.f; dstS = 64; }
    else if (bid < 3216) { src = mlbB + l*32768;   dst = LTmB + l*65536;   K = 32;   N = 1024; ntn = 16; local = bid - 3200; scale = 2.f; dstS = 64; }
    else if (bid < 3232) { src = alaB + l*32768;   dst = LAqB + l*32768;   K = 1024; N = 32;   ntn = 1;  local = bid - 3216; dstS = K; }
    else if (bid < 3248) { src = plaB + l*32768;   dst = LApB + l*32768;   K = 1024; N = 32;   ntn = 1;  local = bid - 3232; dstS = K; }
    else if (bid < 3264) { src = flaB + l*32768;   dst = LAfB + l*32768;   K = 1024; N = 32;   ntn = 1;  local = bid - 3248; dstS = K; }
    else                 { src = mlaB + l*131072;  dst = LAmB + l*131072;  K = 4096; N = 32;   ntn = 1;  local = bid - 3264; dstS = K; }
    int kt = local / ntn, nt = local % ntn;
    int k0 = kt * 64, n0 = nt * 64;
    __shared__ unsigned short Tl[64][66];
    int tid = threadIdx.x;
    int c4 = (tid & 15) * 4;
#pragma unroll
    for (int p = 0; p < 4; ++p) {
        int kl = p * 16 + (tid >> 4);
        if (k0 + kl < K && n0 + c4 < N) {
            float4 v = *(const float4*)(src + (size_t)(k0 + kl) * N + n0 + c4);
            ushort2 o0, o1;
            o0.x = f2bf(v.x * scale); o0.y = f2bf(v.y * scale);
            o1.x = f2bf(v.z * scale); o1.y = f2bf(v.w * scale);
            *(ushort2*)&Tl[kl][c4] = o0;
            *(ushort2*)&Tl[kl][c4 + 2] = o1;
        }
    }
    __syncthreads();
    int nl = tid >> 2;
    int kc = (tid & 3) * 8;
    if (n0 + nl < N) {
#pragma unroll
        for (int hh = 0; hh < 2; ++hh) {
            int kb = kc + hh * 32;
            if (k0 + kb < K) {
                unsigned short pk[8];
#pragma unroll
                for (int j = 0; j < 8; ++j) {
                    pk[j] = Tl[kb + j][nl];
                }
                *(uint4*)(dst + (size_t)(n0 + nl) * dstS + k0 + kb) = *(const uint4*)pk;
            } else if (k0 + kb < dstS) {
                uint4 z; z.x = 0; z.y = 0; z.z = 0; z.w = 0;
                *(uint4*)(dst + (size_t)(n0 + nl) * dstS + k0 + kb) = z;
            }
        }
    }
}

// ---------------- 128x128 8-phase GEMM (T2+T3+T4+T5, 4 waves) for proj / mproj ----------------
// EPI: 1 = +residual, write f32
template <int EPI>
__global__ __launch_bounds__(256, 1) void k_gemm128(
        const unsigned short* __restrict__ A, const unsigned short* __restrict__ WT,
        const float* __restrict__ bias, const unsigned short* __restrict__ tmpA,
        const unsigned short* __restrict__ lbT, const float* __restrict__ res,
        float* __restrict__ outF, int N, int K) {
    __shared__ unsigned short lds[9 * 4096];
    const int tid = threadIdx.x;
    const int wid = tid >> 6, lane = tid & 63;
    const int wr = wid >> 1, wc = wid & 1;          // 2x2 wave grid
    const int nBase = blockIdx.x * 128, rowBase = blockIdx.y * 128;
    const int nk = (K >> 6) + 1;                    // + LoRA K-tile

    f32x4 acc[4][4];
#pragma unroll
    for (int i = 0; i < 4; ++i)
#pragma unroll
        for (int j = 0; j < 4; ++j) acc[i][j] = f32x4{0.f, 0.f, 0.f, 0.f};

    auto stage = [&](int s) {
        int kt = s >> 2, part = s & 3;
        bool dead = kt >= nk;
        unsigned short* dst = &lds[(dead ? 8 : (s & 7)) * 4096];
        bool isA = part >= 2;
        int half = part & 1;
        bool lora = (kt == nk - 1);
#pragma unroll
        for (int i = 0; i < 2; ++i) {
            int o = ((i * 4 + wid) << 10) + (lane << 4);
            int r = o >> 7;
            int col = ((o & 127) ^ (((o >> 9) & 3) << 5)) >> 1;
            const unsigned short* src;
            if (dead) {
                src = A + (lane << 3);
            } else if (isA) {
                int grow = rowBase + half * 64 + r;
                src = lora ? tmpA + (size_t)grow * 64 + col
                           : A + (size_t)grow * K + kt * 64 + col;
            } else {
                int gcol = nBase + half * 64 + r;
                src = lora ? lbT + (size_t)gcol * 64 + col
                           : WT + (size_t)gcol * K + kt * 64 + col;
            }
            GL2LDS(src, dst + ((i * 4 + wid) << 9));
        }
    };

    stage(0); stage(1); stage(2); stage(3);
    stage(4); stage(5); stage(6);
    asm volatile("s_waitcnt vmcnt(6)" ::: "memory");
    __builtin_amdgcn_s_barrier();

    for (int kt = 0; kt < nk; ++kt) {
        const unsigned short* aPart = &lds[(((kt & 1) << 2) + 2 + wr) * 4096];
        const unsigned short* bPart = &lds[(((kt & 1) << 2) + wc) * 4096];
        bf16x8 bfr[4][2];
#pragma unroll
        for (int p = 0; p < 4; ++p) {
            bf16x8 af[2];
#pragma unroll
            for (int kk = 0; kk < 2; ++kk) {
                int row = p * 16 + (lane & 15);
                int cb = (kk * 64 + ((lane >> 4) << 4)) ^ (((row >> 2) & 3) << 5);
                af[kk] = *(const bf16x8*)&aPart[row * 64 + (cb >> 1)];
            }
            if (p == 0) {
#pragma unroll
                for (int n = 0; n < 4; ++n)
#pragma unroll
                    for (int kk = 0; kk < 2; ++kk) {
                        int row = n * 16 + (lane & 15);
                        int cb = (kk * 64 + ((lane >> 4) << 4)) ^ (((row >> 2) & 3) << 5);
                        bfr[n][kk] = *(const bf16x8*)&bPart[row * 64 + (cb >> 1)];
                    }
            }
            stage(p == 0 ? 4 * (kt + 1) + 3 : 4 * (kt + 2) + (p - 1));
            __builtin_amdgcn_s_barrier();
            __builtin_amdgcn_s_setprio(1);
#pragma unroll
            for (int n = 0; n < 4; ++n)
#pragma unroll
                for (int kk = 0; kk < 2; ++kk)
                    acc[p][n] = __builtin_amdgcn_mfma_f32_16x16x32_bf16(
                        af[kk], bfr[n][kk], acc[p][n], 0, 0, 0);
            __builtin_amdgcn_s_setprio(0);
            if (p == 3) asm volatile("s_waitcnt vmcnt(6)" ::: "memory");
            __builtin_amdgcn_s_barrier();
        }
    }

#pragma unroll
    for (int n = 0; n < 4; ++n) {
        int col = nBase + wc * 64 + n * 16 + (lane & 15);
        float bv = bias[col];
#pragma unroll
        for (int m = 0; m < 4; ++m) {
            int row0 = rowBase + wr * 64 + m * 16 + ((lane >> 4) << 2);
#pragma unroll
            for (int rg = 0; rg < 4; ++rg) {
                int row = row0 + rg;
                float v = acc[m][n][rg] + bv;
                size_t idx = (size_t)row * N + col;
                if (EPI == 1) v += res[idx];
                outF[idx] = v;
            }
        }
    }
}

// ---------------- 256x256 8-phase GEMM (T2+T3+T4+T5) for qkv / fc ----------------
// EPI: 2 = GELU, write bf16 ; 3 = fused head-split + KV fake-quant -> qh/kh/vh
template <int EPI>
__global__ __launch_bounds__(512, 1) void k_gemm256(
        const unsigned short* __restrict__ A, const unsigned short* __restrict__ WT,
        const float* __restrict__ bias, const unsigned short* __restrict__ tmpA,
        const unsigned short* __restrict__ lbT,
        const float* __restrict__ kvmin, const float* __restrict__ kvmax, int layer,
        unsigned short* __restrict__ qh, unsigned short* __restrict__ kh,
        unsigned short* __restrict__ vh,
        float* __restrict__ outF, unsigned short* __restrict__ outH, int N, int K) {
    __shared__ unsigned short lds[9 * 8192];
    const int tid = threadIdx.x;
    const int wid = tid >> 6, lane = tid & 63;
    const int wr = wid >> 2, wc = wid & 3;          // 2x4 wave grid
    const int nBase = blockIdx.x * 256, rowBase = blockIdx.y * 256;
    const int nk = (K >> 6) + 1;                    // + LoRA K-tile

    f32x4 acc[8][4];
#pragma unroll
    for (int i = 0; i < 8; ++i)
#pragma unroll
        for (int j = 0; j < 4; ++j) acc[i][j] = f32x4{0.f, 0.f, 0.f, 0.f};

    auto stage = [&](int s) {
        int kt = s >> 2, part = s & 3;
        bool dead = kt >= nk;
        unsigned short* dst = &lds[(dead ? 8 : (s & 7)) * 8192];
        bool isA = part >= 2;
        int half = part & 1;
        bool lora = (kt == nk - 1);
#pragma unroll
        for (int i = 0; i < 2; ++i) {
            int o = ((i * 8 + wid) << 10) + (lane << 4);
            int r = o >> 7;
            int col = ((o & 127) ^ (((o >> 9) & 3) << 5)) >> 1;
            const unsigned short* src;
            if (dead) {
                src = A + (lane << 3);
            } else if (isA) {
                int grow = rowBase + half * 128 + r;
                src = lora ? tmpA + (size_t)grow * 64 + col
                           : A + (size_t)grow * K + kt * 64 + col;
            } else {
                int gcol = nBase + half * 128 + r;
                src = lora ? lbT + (size_t)gcol * 64 + col
                           : WT + (size_t)gcol * K + kt * 64 + col;
            }
            GL2LDS(src, dst + ((i * 8 + wid) << 9));
        }
    };

    stage(0); stage(1); stage(2); stage(3);
    stage(4); stage(5); stage(6);
    asm volatile("s_waitcnt vmcnt(6)" ::: "memory");
    __builtin_amdgcn_s_barrier();

    for (int kt = 0; kt < nk; ++kt) {
        const unsigned short* aPart = &lds[(((kt & 1) << 2) + 2 + wr) * 8192];
        const unsigned short* bPart = &lds[(((kt & 1) << 2) + (wc >> 1)) * 8192];
        bf16x8 bfr[4][2];
#pragma unroll
        for (int p = 0; p < 4; ++p) {
            bf16x8 af[2][2];
#pragma unroll
            for (int mm = 0; mm < 2; ++mm)
#pragma unroll
                for (int kk = 0; kk < 2; ++kk) {
                    int row = (p * 2 + mm) * 16 + (lane & 15);
                    int cb = (kk * 64 + ((lane >> 4) << 4)) ^ (((row >> 2) & 3) << 5);
                    af[mm][kk] = *(const bf16x8*)&aPart[row * 64 + (cb >> 1)];
                }
            if (p == 0) {
#pragma unroll
                for (int n = 0; n < 4; ++n)
#pragma unroll
                    for (int kk = 0; kk < 2; ++kk) {
                        int row = ((wc & 1) << 6) + n * 16 + (lane & 15);
                        int cb = (kk * 64 + ((lane >> 4) << 4)) ^ (((row >> 2) & 3) << 5);
                        bfr[n][kk] = *(const bf16x8*)&bPart[row * 64 + (cb >> 1)];
                    }
            }
            stage(p == 0 ? 4 * (kt + 1) + 3 : 4 * (kt + 2) + (p - 1));
            __builtin_amdgcn_s_barrier();
            __builtin_amdgcn_s_setprio(1);
#pragma unroll
            for (int mm = 0; mm < 2; ++mm)
#pragma unroll
                for (int n = 0; n < 4; ++n)
#pragma unroll
                    for (int kk = 0; kk < 2; ++kk)
                        acc[p * 2 + mm][n] = __builtin_amdgcn_mfma_f32_16x16x32_bf16(
                            af[mm][kk], bfr[n][kk], acc[p * 2 + mm][n], 0, 0, 0);
            __builtin_amdgcn_s_setprio(0);
            if (p == 3) asm volatile("s_waitcnt vmcnt(6)" ::: "memory");
            __builtin_amdgcn_s_barrier();
        }
    }

    if (EPI == 3) {
        const int b = rowBase >> 10, t0 = rowBase & 1023;
        const int sec = nBase >> 10, nb = nBase & 1023;
        const int lrow = lane & 15, lq4 = (lane >> 4) << 2;
        float qs = 1.f, qzp = 0.f, qinv = 1.f;
        if (sec) {
            float mnv = kvmin[layer], mxv = kvmax[layer];
            qs = (mxv - mnv) * (1.f / 255.f);
            qzp = rintf(-mnv / qs);
            qinv = 1.f / qs;
        }
#pragma unroll
        for (int n = 0; n < 4; ++n) {
            int dd = wc * 64 + n * 16 + lrow;
            float bv = bias[nBase + dd];
#pragma unroll
            for (int m = 0; m < 8; ++m) {
#pragma unroll
                for (int rg = 0; rg < 4; ++rg) {
                    int tt = wr * 128 + m * 16 + lq4 + rg;
                    float v = acc[m][n][rg] + bv;
                    if (sec) {
                        float qv = rintf(v * qinv) + qzp;
                        qv = fminf(fmaxf(qv, 0.f), 255.f);
                        v = (qv - qzp) * qs;
                    }
                    int r = (sec == 2) ? dd : tt;
                    int c = (sec == 2) ? tt : dd;
                    lds[r * 256 + (c ^ ((r & 7) << 3))] = f2bf(v);
                }
            }
        }
        __syncthreads();
        if (sec < 2) {
            unsigned short* dstp = sec ? kh : qh;
            int tL = tid & 255;
            int hp = tid >> 8;
#pragma unroll
            for (int hi = 0; hi < 2; ++hi) {
                int dL = (hp * 2 + hi) * 64;
                int hh = (nb >> 6) + hp * 2 + hi;
                size_t base = (((size_t)(b * 16 + hh)) * 1024 + t0 + tL) * 64;
#pragma unroll
                for (int j = 0; j < 8; ++j) {
                    int c = (dL + j * 8) ^ ((tL & 7) << 3);
                    *(uint4*)(dstp + base + j * 8) = *(const uint4*)&lds[tL * 256 + c];
                }
            }
        } else {
            int dL = tid & 255;
            int th = (tid >> 8) * 128;
            int hh = (nb >> 6) + (dL >> 6);
            size_t base = (((size_t)(b * 16 + hh)) * 64 + (dL & 63)) * 1024 + t0 + th;
#pragma unroll
            for (int j = 0; j < 16; ++j) {
                int c = (th + j * 8) ^ ((dL & 7) << 3);
                *(uint4*)(vh + base + j * 8) = *(const uint4*)&lds[dL * 256 + c];
            }
        }
    } else {
#pragma unroll
        for (int n = 0; n < 4; ++n) {
            int col = nBase + wc * 64 + n * 16 + (lane & 15);
            float bv = bias[col];
#pragma unroll
            for (int m = 0; m < 8; ++m) {
                int row0 = rowBase + wr * 128 + m * 16 + ((lane >> 4) << 2);
#pragma unroll
                for (int rg = 0; rg < 4; ++rg) {
                    int row = row0 + rg;
                    float v = acc[m][n][rg] + bv;
                    size_t idx = (size_t)row * N + col;
                    v = 0.5f * v * (1.f + erff(v * 0.70710678118654752f));
                    outH[idx] = f2bf(v);
                }
            }
        }
    }
}

// ---------------- flash attention (causal), 64 q-rows/block, 4 waves ----------------
// swapped QK^T; tree reductions for max/sum
__global__ __launch_bounds__(256) void k_attn(const unsigned short* __restrict__ qh,
        const unsigned short* __restrict__ kh, const unsigned short* __restrict__ vh,
        unsigned short* __restrict__ o) {
    int fid = blockIdx.y * 16 + blockIdx.x;
    int wgid = (fid & 7) * 128 + (fid >> 3);
    int bh = wgid >> 4, qb = wgid & 15;
    int b = bh >> 4, hh = bh & 15;
    int tid = threadIdx.x, w = tid >> 6, lane = tid & 63;
    int cq = lane & 15;
    int g = lane >> 4;
    int lk8 = g * 8;
    __shared__ unsigned short Kl[64][72];
    __shared__ unsigned short Vt[64][72];
    __shared__ unsigned short Pl[4][16][72];
    const float SCL = 0.18033688011112042f;   // 0.125 * log2(e)
    int qrow = qb * 64 + w * 16 + cq;
    bf16x8 aq[2];
    aq[0] = *(const bf16x8*)(qh + ((size_t)bh * 1024 + qrow) * 64 + lk8);
    aq[1] = *(const bf16x8*)(qh + ((size_t)bh * 1024 + qrow) * 64 + 32 + lk8);
    f32x4 od[4];
#pragma unroll
    for (int i = 0; i < 4; ++i) od[i] = f32x4{0.f, 0.f, 0.f, 0.f};
    float mrun = -3e38f, lrun = 0.f;
    int rl = tid >> 2, seg = (tid & 3) * 16;
    for (int kb = 0; kb <= qb; ++kb) {
        __syncthreads();
        {
            size_t kbase = ((size_t)bh * 1024 + kb * 64 + rl) * 64 + seg;
            *(uint4*)&Kl[rl][seg] = *(const uint4*)(kh + kbase);
            *(uint4*)&Kl[rl][seg + 8] = *(const uint4*)(kh + kbase + 8);
            size_t vbase = ((size_t)bh * 64 + rl) * 1024 + kb * 64 + seg;
            *(uint4*)&Vt[rl][seg] = *(const uint4*)(vh + vbase);
            *(uint4*)&Vt[rl][seg + 8] = *(const uint4*)(vh + vbase + 8);
        }
        __syncthreads();
        f32x4 st[4];
#pragma unroll
        for (int ktile = 0; ktile < 4; ++ktile) {
            f32x4 sacc = f32x4{0.f, 0.f, 0.f, 0.f};
#pragma unroll
            for (int dh = 0; dh < 2; ++dh) {
                bf16x8 bk = *(const bf16x8*)&Kl[ktile * 16 + cq][dh * 32 + lk8];
                sacc = __builtin_amdgcn_mfma_f32_16x16x32_bf16(bk, aq[dh], sacc, 0, 0, 0);
            }
            st[ktile] = sacc * SCL;
        }
        if (kb == qb) {
#pragma unroll
            for (int ktile = 0; ktile < 4; ++ktile) {
#pragma unroll
                for (int rg = 0; rg < 4; ++rg) {
                    int kidx = kb * 64 + ktile * 16 + g * 4 + rg;
                    if (kidx > qrow) st[ktile][rg] = -3e38f;
                }
            }
        }
        float tm[4];
#pragma unroll
        for (int ktile = 0; ktile < 4; ++ktile)
            tm[ktile] = fmaxf(fmaxf(st[ktile][0], st[ktile][1]),
                              fmaxf(st[ktile][2], st[ktile][3]));
        float pmax = fmaxf(fmaxf(tm[0], tm[1]), fmaxf(tm[2], tm[3]));
        pmax = fmaxf(pmax, __shfl_xor(pmax, 16));
        pmax = fmaxf(pmax, __shfl_xor(pmax, 32));
        float mnew = fmaxf(mrun, pmax);
#pragma unroll
        for (int ktile = 0; ktile < 4; ++ktile)
#pragma unroll
            for (int rg = 0; rg < 4; ++rg)
                st[ktile][rg] = exp2f(st[ktile][rg] - mnew);
        float ts[4];
#pragma unroll
        for (int ktile = 0; ktile < 4; ++ktile)
            ts[ktile] = (st[ktile][0] + st[ktile][1]) + (st[ktile][2] + st[ktile][3]);
        float sum = (ts[0] + ts[1]) + (ts[2] + ts[3]);
        sum += __shfl_xor(sum, 16);
        sum += __shfl_xor(sum, 32);
        float corr = exp2f(mrun - mnew);
        lrun = lrun * corr + sum;
        mrun = mnew;
#pragma unroll
        for (int rg = 0; rg < 4; ++rg) {
            float cv = __shfl(corr, (lane & 48) | (g * 4 + rg));
#pragma unroll
            for (int dt = 0; dt < 4; ++dt) od[dt][rg] *= cv;
        }
#pragma unroll
        for (int ktile = 0; ktile < 4; ++ktile) {
            ushort4 pw;
            pw.x = f2bf(st[ktile][0]); pw.y = f2bf(st[ktile][1]);
            pw.z = f2bf(st[ktile][2]); pw.w = f2bf(st[ktile][3]);
            *(ushort4*)&Pl[w][cq][ktile * 16 + g * 4] = pw;
        }
        bf16x8 pa[2];
        pa[0] = *(const bf16x8*)&Pl[w][cq][lk8];
        pa[1] = *(const bf16x8*)&Pl[w][cq][32 + lk8];
#pragma unroll
        for (int dt = 0; dt < 4; ++dt) {
#pragma unroll
            for (int kh2 = 0; kh2 < 2; ++kh2) {
                bf16x8 bv = *(const bf16x8*)&Vt[dt * 16 + cq][kh2 * 32 + lk8];
                od[dt] = __builtin_amdgcn_mfma_f32_16x16x32_bf16(pa[kh2], bv, od[dt], 0, 0, 0);
            }
        }
    }
#pragma unroll
    for (int rg = 0; rg < 4; ++rg) {
        float lv = __shfl(lrun, (lane & 48) | (g * 4 + rg));
        float inv = 1.0f / lv;
        int row = qb * 64 + w * 16 + g * 4 + rg;
#pragma unroll
        for (int dt = 0; dt < 4; ++dt) {
            float val = od[dt][rg] * inv;
            o[((size_t)(b * 1024 + row)) * 1024 + hh * 64 + dt * 16 + cq] = f2bf(val);
        }
    }
}

// ---------------- host orchestration ----------------
extern "C" void kernel_launch(void* const* d_in, const int* in_sizes, int n_in,
                              void* d_out, int out_size, void* d_ws, size_t ws_size,
                              hipStream_t stream) {
    const int*   ids      = (const int*)d_in[0];
    const float* wte      = (const float*)d_in[1];
    const float* wpe      = (const float*)d_in[2];
    const float* ln1_g    = (const float*)d_in[3];
    const float* ln1_b    = (const float*)d_in[4];
    const float* attn_w   = (const float*)d_in[5];
    const float* attn_b   = (const float*)d_in[6];
    const float* attn_la  = (const float*)d_in[7];
    const float* attn_lb  = (const float*)d_in[8];
    const float* proj_w   = (const float*)d_in[9];
    const float* proj_b   = (const float*)d_in[10];
    const float* proj_la  = (const float*)d_in[11];
    const float* proj_lb  = (const float*)d_in[12];
    const float* ln2_g    = (const float*)d_in[13];
    const float* ln2_b    = (const float*)d_in[14];
    const float* fc_w     = (const float*)d_in[15];
    const float* fc_b     = (const float*)d_in[16];
    const float* fc_la    = (const float*)d_in[17];
    const float* fc_lb    = (const float*)d_in[18];
    const float* mproj_w  = (const float*)d_in[19];
    const float* mproj_b  = (const float*)d_in[20];
    const float* mproj_la = (const float*)d_in[21];
    const float* mproj_lb = (const float*)d_in[22];
    const float* kv_min   = (const float*)d_in[23];
    const float* kv_max   = (const float*)d_in[24];
    const float* lnf_g    = (const float*)d_in[25];
    const float* lnf_b    = (const float*)d_in[26];

    char* ws = (char*)d_ws;
    size_t off = 0;
    auto alloc = [&](size_t bytes) -> char* {
        char* p = ws + off;
        off = (off + bytes + 255) & ~(size_t)255;
        return p;
    };
    float*          h   = (float*)alloc(4096ull * 1024 * 4);
    unsigned short* xb  = (unsigned short*)alloc(4096ull * 1024 * 2);
    unsigned short* tmp = (unsigned short*)alloc(4096ull * 64 * 2);
    unsigned short* qhb = (unsigned short*)alloc(64ull * 1024 * 64 * 2);
    unsigned short* khb = (unsigned short*)alloc(64ull * 1024 * 64 * 2);
    unsigned short* vhb = (unsigned short*)alloc(64ull * 64 * 1024 * 2);
    unsigned short* ob  = (unsigned short*)alloc(4096ull * 1024 * 2);
    unsigned short* mb  = (unsigned short*)alloc(4096ull * 4096 * 2);
    unsigned short* WTq = (unsigned short*)alloc(12ull * 3072 * 1024 * 2);
    unsigned short* WTp = (unsigned short*)alloc(12ull * 1024 * 1024 * 2);
    unsigned short* WTf = (unsigned short*)alloc(12ull * 4096 * 1024 * 2);
    unsigned short* WTm = (unsigned short*)alloc(12ull * 1024 * 4096 * 2);
    unsigned short* LTq = (unsigned short*)alloc(12ull * 3072 * 64 * 2);
    unsigned short* LTp = (unsigned short*)alloc(12ull * 1024 * 64 * 2);
    unsigned short* LTf = (unsigned short*)alloc(12ull * 4096 * 64 * 2);
    unsigned short* LTm = (unsigned short*)alloc(12ull * 1024 * 64 * 2);
    unsigned short* LAq = (unsigned short*)alloc(12ull * 32 * 1024 * 2);
    unsigned short* LAp = (unsigned short*)alloc(12ull * 32 * 1024 * 2);
    unsigned short* LAf = (unsigned short*)alloc(12ull * 32 * 1024 * 2);
    unsigned short* LAm = (unsigned short*)alloc(12ull * 32 * 4096 * 2);

    k_embed<<<4096, 256, 0, stream>>>(ids, wte, wpe, h);
    k_prep<<<dim3(3328, 12), 256, 0, stream>>>(
        attn_w, proj_w, fc_w, mproj_w,
        attn_lb, proj_lb, fc_lb, mproj_lb,
        attn_la, proj_la, fc_la, mproj_la,
        WTq, WTp, WTf, WTm, LTq, LTp, LTf, LTm, LAq, LAp, LAf, LAm);
    for (int l = 0; l < 12; ++l) {
        k_ln_lora<<<256, 512, 0, stream>>>(h, ln1_g + l * 1024, ln1_b + l * 1024,
                                           LAq + (size_t)l * 32768, xb, tmp);
        k_gemm256<3><<<dim3(12, 16), 512, 0, stream>>>(xb, WTq + (size_t)l * 3145728,
                                                       attn_b + l * 3072, tmp, LTq + (size_t)l * 196608,
                                                       kv_min, kv_max, l, qhb, khb, vhb,
                                                       nullptr, nullptr, 3072, 1024);
        k_attn<<<dim3(16, 64), 256, 0, stream>>>(qhb, khb, vhb, ob);
        k_lora_mfma<<<256, 256, 0, stream>>>(ob, LAp + (size_t)l * 32768, tmp, 1024);
        k_gemm128<1><<<dim3(8, 32), 256, 0, stream>>>(ob, WTp + (size_t)l * 1048576,
                                                      proj_b + l * 1024, tmp, LTp + (size_t)l * 65536,
                                                      h, h, 1024, 1024);
        k_ln_lora<<<256, 512, 0, stream>>>(h, ln2_g + l * 1024, ln2_b + l * 1024,
                                           LAf + (size_t)l * 32768, xb, tmp);
        k_gemm256<2><<<dim3(16, 16), 512, 0, stream>>>(xb, WTf + (size_t)l * 4194304,
                                                       fc_b + l * 4096, tmp, LTf + (size_t)l * 262144,
                                                       nullptr, nullptr, 0, nullptr, nullptr, nullptr,
                                                       nullptr, mb, 4096, 1024);
        k_lora_mfma<<<256, 256, 0, stream>>>(mb, LAm + (size_t)l * 131072, tmp, 4096);
        k_gemm128<1><<<dim3(8, 32), 256, 0, stream>>>(mb, WTm + (size_t)l * 4194304,
                                                      mproj_b + l * 1024, tmp, LTm + (size_t)l * 65536,
                                                      h, h, 1024, 4096);
    }
    k_lnf<<<4096, 256, 0, stream>>>(h, lnf_g, lnf_b, (float*)d_out);
}